// Round 17
// baseline (210.110 us; speedup 1.0000x reference)
//
#include <hip/hip_runtime.h>
#include <math.h>

#define E_N   8192
#define HID   128
#define NRAD  64
#define KNB   32
#define CUTF  10.0f
#define LNEPS 1e-5f

typedef unsigned short u16;
typedef unsigned int   u32;
typedef unsigned long long u64;
typedef __bf16 bf16x8 __attribute__((ext_vector_type(8)));
typedef u16    u16x8  __attribute__((ext_vector_type(8)));
typedef float  f32x4  __attribute__((ext_vector_type(4)));

__device__ __forceinline__ u16 f2bf(float f) {          // native HW cvt (RNE)
  __bf16 h = (__bf16)f;
  return __builtin_bit_cast(u16, h);
}
__device__ __forceinline__ float bf2f(u16 v) {
  return __uint_as_float(((u32)v) << 16);
}

__device__ __forceinline__ u64 shflx64(u64 v, int m) {
  int lo = __shfl_xor((int)(v & 0xffffffffull), m, 64);
  int hi = __shfl_xor((int)(v >> 32), m, 64);
  return ((u64)(unsigned)hi << 32) | (unsigned)lo;
}

// monotone-u32 key of squared distance; fmaf-pinned so pass1/pass2 agree bitwise
__device__ __forceinline__ u32 d2key(const float4 me, const float4 c) {
  float dot = fmaf(me.x, c.x, fmaf(me.y, c.y, me.z * c.z));
  float d2  = fmaf(-2.0f, dot, me.w + c.w);     // gram trick, as in reference
  u32 u = __float_as_uint(d2);
  return u ^ (((u32)((int)u >> 31)) | 0x80000000u);
}

// ---------------- kernel 0: merged prep (bf16 panels / fused products / centers) ----------------
__global__ __launch_bounds__(256) void k_pre(
    const float* __restrict__ W1, const float* __restrict__ W2,
    const float* __restrict__ Wq, const float* __restrict__ Wk,
    const float* __restrict__ Wv, const float* __restrict__ Wg1,
    const float* __restrict__ nc, const int* __restrict__ ei,
    u16* __restrict__ Wt1r, u16* __restrict__ Wt2,
    u16* __restrict__ Wqt, u16* __restrict__ Wkt, u16* __restrict__ Wvt,
    u16* __restrict__ Wqct, u16* __restrict__ Wkct, u16* __restrict__ Wvgt,
    float4* __restrict__ cen4) {
  const int b = blockIdx.x, t = threadIdx.x;
  if (b < 128) {
    if (t < 64)       Wt1r[b*64 + t]      = f2bf(W1[(256+t)*HID + b]);   // rbf rows 256..319
    else if (t < 192) Wt2[b*HID + (t-64)] = f2bf(W2[(t-64)*HID + b]);
  } else if (b < 256) {
    const int r = b - 128, o = t & 127;
    float a = 0.f;
    if (t < 128) {
      #pragma unroll 8
      for (int m = 0; m < 128; ++m) a = fmaf(Wq[r*128+m], W1[m*128+o], a);
      Wqct[o*128 + r] = f2bf(a);
    } else {
      #pragma unroll 8
      for (int m = 0; m < 128; ++m) a = fmaf(Wk[r*128+m], W1[(128+m)*128+o], a);
      Wkct[o*128 + r] = f2bf(a);
    }
  } else if (b < 384) {
    const int r = b - 256;
    if (t < 128) {
      float a = 0.f;
      #pragma unroll 8
      for (int m = 0; m < 128; ++m) a = fmaf(Wv[r*128+m], Wg1[m*128+t], a);
      Wvgt[t*128 + r] = f2bf(a);
    }
  } else if (b < 512) {
    const int c = b - 384;
    if (t < 128) Wqt[c*128 + t]       = f2bf(Wq[t*128 + c]);
    else         Wkt[c*128 + (t-128)] = f2bf(Wk[(t-128)*128 + c]);
  } else if (b < 640) {
    const int c = b - 512;
    if (t < 128) Wvt[c*128 + t] = f2bf(Wv[t*128 + c]);
  } else {
    const int e = (b - 640)*256 + t;
    if (e < E_N) {
      int a = ei[e], bb = ei[E_N + e];
      float x = (nc[a*3+0] + nc[bb*3+0]) * 0.5f;
      float y = (nc[a*3+1] + nc[bb*3+1]) * 0.5f;
      float z = (nc[a*3+2] + nc[bb*3+2]) * 0.5f;
      cen4[e] = make_float4(x, y, z, x*x + y*y + z*z);
    }
  }
}

// ---------------- kernel 1: spatial counting sort of edges (256 buckets) ----------------
// eperm = edge ids ordered by spatial bucket of center. Single block.
__global__ __launch_bounds__(256) void k_sort(const float4* __restrict__ cen4,
                                              int* __restrict__ eperm) {
  __shared__ u32 hist[256], base[256], wred[4];
  const int t = threadIdx.x;
  const int lane = t & 63, w = t >> 6;
  hist[t] = 0;
  __syncthreads();
  u32 keys[32];
  #pragma unroll
  for (int s = 0; s < 32; ++s) {
    float4 c = cen4[t + (s << 8)];
    int qx = (int)((c.x + 8.0f) * 0.5f);  qx = qx < 0 ? 0 : (qx > 7 ? 7 : qx);
    int qy = (int)((c.y + 8.0f) * 0.5f);  qy = qy < 0 ? 0 : (qy > 7 ? 7 : qy);
    int qz = (int)((c.z + 8.0f) * 0.25f); qz = qz < 0 ? 0 : (qz > 3 ? 3 : qz);
    u32 key = ((u32)qx << 5) | ((u32)qy << 2) | (u32)qz;
    keys[s] = key;
    atomicAdd(&hist[key], 1u);
  }
  __syncthreads();
  // exclusive scan over 256 bins (thread t owns bin t)
  u32 h = hist[t];
  int inc = (int)h;
  #pragma unroll
  for (int off = 1; off < 64; off <<= 1) {
    int v = __shfl_up(inc, off, 64);
    if (lane >= off) inc += v;
  }
  if (lane == 63) wred[w] = (u32)inc;
  __syncthreads();
  u32 woff = 0;
  #pragma unroll
  for (int ww = 0; ww < 4; ++ww) woff += (ww < w) ? wred[ww] : 0u;
  base[t] = woff + (u32)inc - h;
  __syncthreads();
  #pragma unroll
  for (int s = 0; s < 32; ++s) {
    u32 pos = atomicAdd(&base[keys[s]], 1u);
    eperm[pos] = t + (s << 8);
  }
}

// ---------------- kernel 2: top-K, 8 rows/block, two-pass prune + exact lex rank ----------------
__global__ __launch_bounds__(256) void k_topk(const float4* __restrict__ cen4,
                                              int* __restrict__ idxo) {
  const int row0 = blockIdx.x * 8;
  const int t = threadIdx.x;
  const int lane = t & 63, w = t >> 6;
  __shared__ __align__(16) u32 smin[8][256];   // 8 KiB
  __shared__ __align__(16) u64 comp[2048];     // 16 KiB survivor buffer
  __shared__ u32 sU[8];
  __shared__ u32 scnt, scnt_r[8];
  __shared__ u64 wred[4];
  __shared__ u64 winner;

  if (t == 0) scnt = 0;
  if (t < 8) scnt_r[t] = 0;

  float4 me[8];
  #pragma unroll
  for (int r = 0; r < 8; ++r) me[r] = cen4[row0 + r];

  // ---- pass 1: running mins for 8 rows ----
  u32 mn[8];
  #pragma unroll
  for (int r = 0; r < 8; ++r) mn[r] = 0xFFFFFFFFu;
  for (int s = 0; s < 32; ++s) {
    float4 c = cen4[t + (s << 8)];
    #pragma unroll
    for (int r = 0; r < 8; ++r) {
      u32 k = d2key(me[r], c);
      mn[r] = k < mn[r] ? k : mn[r];
    }
  }
  #pragma unroll
  for (int r = 0; r < 8; ++r) smin[r][t] = mn[r];
  __syncthreads();

  // ---- per-row bound: wave w handles rows 2w, 2w+1; in-wave radix bisect ----
  #pragma unroll
  for (int rr = 0; rr < 2; ++rr) {
    const int r = w*2 + rr;
    uint4 vv = *(const uint4*)&smin[r][lane*4];
    u32 P = 0;
    u32 rem = 31;
    #pragma unroll 1
    for (int b = 31; b >= 12; --b) {
      u32 bit = 1u << b;
      bool pm0 = ((u64)(vv.x ^ P) >> (b+1)) == 0ull;
      bool pm1 = ((u64)(vv.y ^ P) >> (b+1)) == 0ull;
      bool pm2 = ((u64)(vv.z ^ P) >> (b+1)) == 0ull;
      bool pm3 = ((u64)(vv.w ^ P) >> (b+1)) == 0ull;
      u32 c0 = (u32)__popcll(__ballot(pm0 && !(vv.x & bit)))
             + (u32)__popcll(__ballot(pm1 && !(vv.y & bit)))
             + (u32)__popcll(__ballot(pm2 && !(vv.z & bit)))
             + (u32)__popcll(__ballot(pm3 && !(vv.w & bit)));
      if (rem >= c0) { P |= bit; rem -= c0; }
    }
    if (lane == 0) sU[r] = P | 0xFFFu;
  }
  __syncthreads();

  // ---- pass 2: recompute keys, compact survivors ----
  u32 Ur[8];
  #pragma unroll
  for (int r = 0; r < 8; ++r) Ur[r] = sU[r];
  for (int s = 0; s < 32; ++s) {
    float4 c = cen4[t + (s << 8)];
    #pragma unroll
    for (int r = 0; r < 8; ++r) {
      u32 k = d2key(me[r], c);
      if (k <= Ur[r]) {
        u32 pos = atomicAdd(&scnt, 1u);
        atomicAdd(&scnt_r[r], 1u);
        if (pos < 2048u)
          comp[pos] = ((u64)r << 45) | (((u64)k) << 13) | (u32)(t + (s << 8));
      }
    }
  }
  __syncthreads();
  const int cnt = (int)scnt;

  if (cnt <= 2048) {
    u32 off[8];
    off[0] = 0;
    #pragma unroll
    for (int r = 1; r < 8; ++r) off[r] = off[r-1] + scnt_r[r-1];
    for (int i = t; i < cnt; i += 256) {
      u64 mev = comp[i];
      int rk = 0;
      int j2 = 0;
      for (; j2 + 2 <= cnt; j2 += 2) {
        ulonglong2 pr = *(const ulonglong2*)&comp[j2];
        rk += (pr.x < mev) ? 1 : 0;
        rk += (pr.y < mev) ? 1 : 0;
      }
      if (j2 < cnt) rk += (comp[j2] < mev) ? 1 : 0;
      int r = (int)(mev >> 45);
      int rank = rk - (int)off[r];
      if (rank < KNB) idxo[(row0 + r)*KNB + rank] = (int)(mev & 0x1FFFull);
    }
  } else {
    // overflow fallback (never taken statistically): exact per-row extract-min
    for (int r = 0; r < 8; ++r) {
      float4 mer = cen4[row0 + r];
      u32 taken = 0;
      for (int kk2 = 0; kk2 < KNB; ++kk2) {
        u64 lk = 0xFFFFFFFFFFFFFFFFull;
        for (int s = 0; s < 32; ++s) {
          if (taken & (1u << s)) continue;
          float4 c = cen4[t + (s << 8)];
          u64 kx = (((u64)d2key(mer, c)) << 13) | (u32)(t + (s << 8));
          lk = kx < lk ? kx : lk;
        }
        #pragma unroll
        for (int m = 1; m < 64; m <<= 1) {
          u64 o = shflx64(lk, m);
          lk = o < lk ? o : lk;
        }
        if (lane == 0) wred[w] = lk;
        __syncthreads();
        if (t == 0) {
          u64 w0 = wred[0] < wred[1] ? wred[0] : wred[1];
          u64 w1 = wred[2] < wred[3] ? wred[2] : wred[3];
          winner = w0 < w1 ? w0 : w1;
          idxo[(row0 + r)*KNB + kk2] = (int)(winner & 0x1FFFull);
        }
        __syncthreads();
        u64 jw = winner & 0x1FFFull;
        if (((u32)jw & 255u) == (u32)t) taken |= 1u << ((u32)jw >> 8);
        __syncthreads();
      }
    }
  }
}

// ---------------- kernel 3: 6-panel MFMA projections, 32 edges/block ----------------
__global__ __launch_bounds__(256) void k_qkv(const float* __restrict__ ef,
    const u16* __restrict__ Wqt, const u16* __restrict__ Wkt, const u16* __restrict__ Wvt,
    const u16* __restrict__ Wqct, const u16* __restrict__ Wkct, const u16* __restrict__ Wvgt,
    const float* __restrict__ b1, const float* __restrict__ bg1,
    const float* __restrict__ Wg2, const float* __restrict__ bg2,
    float* __restrict__ qf, float* __restrict__ qW1,
    u16* __restrict__ kjp, u16* __restrict__ vfb, float* __restrict__ gates) {
  __shared__ u16 sE[32*128];      // ef tile bf16, swizzled (8 KiB)
  __shared__ float spart[4][32];
  const int t = threadIdx.x;
  const int w = t >> 6, l = t & 63;
  const int l15 = l & 15, l4 = l >> 4;
  const int e0 = blockIdx.x * 32;
  const int colw = w * 32;

  // stage ef tile
  {
    const int srow = t >> 3, sb = t & 7;
    const float4* src = (const float4*)(ef + (size_t)(e0 + srow)*HID + sb*16);
    #pragma unroll
    for (int g = 0; g < 2; ++g) {
      float4 v0 = src[g*2], v1 = src[g*2+1];
      u16x8 vv;
      vv[0]=f2bf(v0.x); vv[1]=f2bf(v0.y); vv[2]=f2bf(v0.z); vv[3]=f2bf(v0.w);
      vv[4]=f2bf(v1.x); vv[5]=f2bf(v1.y); vv[6]=f2bf(v1.z); vv[7]=f2bf(v1.w);
      int widx = (srow*128 + sb*16 + g*8) ^ ((srow & 7) << 3);
      *(u16x8*)(&sE[widx]) = vv;
    }
  }
  __syncthreads();

  // preload all A fragments (2 row-tiles x 4 k-slices)
  bf16x8 afq[2][4];
  #pragma unroll
  for (int rt = 0; rt < 2; ++rt) {
    int row = rt*16 + l15;
    #pragma unroll
    for (int ks = 0; ks < 4; ++ks) {
      int aidx = (row*128 + ks*32 + l4*8) ^ ((row & 7) << 3);
      afq[rt][ks] = *(const bf16x8*)(&sE[aidx]);
    }
  }

  f32x4 a2[2][2];
  auto gemm_panel = [&](const u16* __restrict__ P) {
    #pragma unroll
    for (int rt = 0; rt < 2; ++rt)
      #pragma unroll
      for (int ct = 0; ct < 2; ++ct) a2[rt][ct] = (f32x4){0.f,0.f,0.f,0.f};
    #pragma unroll
    for (int ks = 0; ks < 4; ++ks) {
      bf16x8 bfr[2];
      #pragma unroll
      for (int ct = 0; ct < 2; ++ct)
        bfr[ct] = *(const bf16x8*)(&P[(colw + ct*16 + l15)*128 + ks*32 + l4*8]);
      #pragma unroll
      for (int rt = 0; rt < 2; ++rt)
        #pragma unroll
        for (int ct = 0; ct < 2; ++ct)
          a2[rt][ct] = __builtin_amdgcn_mfma_f32_16x16x32_bf16(afq[rt][ks], bfr[ct], a2[rt][ct], 0, 0, 0);
    }
  };

  // q
  gemm_panel(Wqt);
  #pragma unroll
  for (int rt = 0; rt < 2; ++rt)
    #pragma unroll
    for (int r = 0; r < 4; ++r) {
      size_t e = e0 + rt*16 + l4*4 + r;
      #pragma unroll
      for (int ct = 0; ct < 2; ++ct)
        qf[e*HID + colw + ct*16 + l15] = a2[rt][ct][r];
    }
  // k
  gemm_panel(Wkt);
  #pragma unroll
  for (int rt = 0; rt < 2; ++rt)
    #pragma unroll
    for (int r = 0; r < 4; ++r) {
      size_t e = e0 + rt*16 + l4*4 + r;
      #pragma unroll
      for (int ct = 0; ct < 2; ++ct)
        kjp[e*256 + 128 + colw + ct*16 + l15] = f2bf(a2[rt][ct][r]);
    }
  // v
  gemm_panel(Wvt);
  #pragma unroll
  for (int rt = 0; rt < 2; ++rt)
    #pragma unroll
    for (int r = 0; r < 4; ++r) {
      size_t e = e0 + rt*16 + l4*4 + r;
      #pragma unroll
      for (int ct = 0; ct < 2; ++ct)
        vfb[e*HID + colw + ct*16 + l15] = f2bf(a2[rt][ct][r]);
    }
  // qW1 = ef@(Wq@W1q) + b1
  gemm_panel(Wqct);
  {
    float b1r[2];
    #pragma unroll
    for (int ct = 0; ct < 2; ++ct) b1r[ct] = b1[colw + ct*16 + l15];
    #pragma unroll
    for (int rt = 0; rt < 2; ++rt)
      #pragma unroll
      for (int r = 0; r < 4; ++r) {
        size_t e = e0 + rt*16 + l4*4 + r;
        #pragma unroll
        for (int ct = 0; ct < 2; ++ct)
          qW1[e*HID + colw + ct*16 + l15] = a2[rt][ct][r] + b1r[ct];
      }
  }
  // kW1 = ef@(Wk@W1k)
  gemm_panel(Wkct);
  #pragma unroll
  for (int rt = 0; rt < 2; ++rt)
    #pragma unroll
    for (int r = 0; r < 4; ++r) {
      size_t e = e0 + rt*16 + l4*4 + r;
      #pragma unroll
      for (int ct = 0; ct < 2; ++ct)
        kjp[e*256 + colw + ct*16 + l15] = f2bf(a2[rt][ct][r]);
    }
  // gates: g1 = silu(ef@(Wv@Wg1) + bg1); gate = sigmoid(g1.Wg2 + bg2)
  gemm_panel(Wvgt);
  {
    float bgr[2], w3r[2];
    #pragma unroll
    for (int ct = 0; ct < 2; ++ct) {
      int col = colw + ct*16 + l15;
      bgr[ct] = bg1[col]; w3r[ct] = Wg2[col];
    }
    #pragma unroll
    for (int rt = 0; rt < 2; ++rt)
      #pragma unroll
      for (int r = 0; r < 4; ++r) {
        float part = 0.f;
        #pragma unroll
        for (int ct = 0; ct < 2; ++ct) {
          float x = a2[rt][ct][r] + bgr[ct];
          float g = x / (1.0f + __expf(-x));
          part = fmaf(g, w3r[ct], part);
        }
        part += __shfl_xor(part, 1, 64);
        part += __shfl_xor(part, 2, 64);
        part += __shfl_xor(part, 4, 64);
        part += __shfl_xor(part, 8, 64);
        if (l15 == 0) spart[w][rt*16 + l4*4 + r] = part;
      }
  }
  __syncthreads();
  if (t < 32)
    gates[e0 + t] = 1.0f / (1.0f + __expf(-(spart[0][t] + spart[1][t] + spart[2][t] + spart[3][t] + bg2[0])));
}

// ---------------- kernel 5: mega (MLP + softmax + combine + Wo + LayerNorm), 4 edges/block ----------------
// 512 threads = 8 waves. Edges taken from the SPATIAL permutation eperm;
// blocks are XCD-swizzled so each XCD owns one contiguous spatial slab ->
// gather working set per XCD ~1/8 of tables -> L2-resident.
__global__ __launch_bounds__(512) void k_mega(
    const int* __restrict__ idx, const int* __restrict__ eperm,
    const float* __restrict__ qf,
    const float4* __restrict__ cen4,
    const float* __restrict__ qW1, const u16* __restrict__ kjp,
    const u16* __restrict__ vfb, const float* __restrict__ gates,
    const u16* __restrict__ Wt1r, const u16* __restrict__ Wt2,
    const float* __restrict__ W1,
    const float* __restrict__ b2, const float* __restrict__ W3,
    const float* __restrict__ b3,
    const float* __restrict__ centers, const float* __restrict__ widths,
    const float* __restrict__ ef, const float* __restrict__ ec,
    const float* __restrict__ Wo, const float* __restrict__ bo,
    const float* __restrict__ gamma, const float* __restrict__ beta,
    float* __restrict__ outf, float* __restrict__ outc) {
  __shared__ u16 sH[128*128];     // 32 KiB: kW1[j] tile -> in-place h tile
  __shared__ u16 sA[128*64];      // 16 KiB: rbf tile; aliased after GEMM1:
  float* spart = (float*)sA;            // [4][128] col-slab partial scores
  float* sUpd  = (float*)sA + 512;      // [4][128] updated features
  float* swk   = (float*)sA + 1024;     // [4][32]  softmax weights
  float* sred  = (float*)sA + 1152;     // [8][2]   LN partial sums
  __shared__ float sQW[4][128];   // 2 KiB
  __shared__ float sDot[128];
  __shared__ float sDist[128];
  __shared__ int   sIdx[128];
  __shared__ int   sEid[4];

  const int t  = threadIdx.x;
  const int w  = t >> 6, l = t & 63;
  const int l15 = l & 15, l4 = l >> 4;
  const int c4 = w & 3, rh = w >> 2;
  // XCD-affine group: blocks with equal (bid%8) get a contiguous sorted slab
  const int g  = (blockIdx.x & 7) * 256 + (blockIdx.x >> 3);
  const int gb = g * 4;

  // ---- stage: kW1[j] tile (vectorized gather -> sH), dot, dist, rbf -> sA ----
  const int srow = t >> 2, sb = t & 3;      // 128 rows x 4 threads
  const int myE = eperm[gb + (srow >> 5)];  // edge of this row
  const int sj  = idx[myE*KNB + (srow & 31)];
  if (t < 4) sEid[t] = eperm[gb + t];
  {
    const u16x8* kw = (const u16x8*)(kjp + (size_t)sj*256 + sb*32);
    #pragma unroll
    for (int gg = 0; gg < 4; ++gg) {
      int widx = (srow*128 + sb*32 + gg*8) ^ ((srow & 7) << 3);
      *(u16x8*)(&sH[widx]) = kw[gg];
    }
  }
  // q.k dot: q f32 x k bf16 (packed row), 4 lanes/row
  const u16x8* kb = (const u16x8*)(kjp + (size_t)sj*256 + 128 + sb*32);
  const float4* q4 = (const float4*)(qf + (size_t)myE*HID) + sb*8;
  float dt = 0.f;
  #pragma unroll
  for (int i = 0; i < 4; ++i) {
    u16x8 kv8 = kb[i];
    float4 qa = q4[i*2], qb = q4[i*2+1];
    dt += bf2f(kv8[0])*qa.x + bf2f(kv8[1])*qa.y + bf2f(kv8[2])*qa.z + bf2f(kv8[3])*qa.w
        + bf2f(kv8[4])*qb.x + bf2f(kv8[5])*qb.y + bf2f(kv8[6])*qb.z + bf2f(kv8[7])*qb.w;
  }
  dt += __shfl_xor(dt, 1, 64);
  dt += __shfl_xor(dt, 2, 64);
  // geometry
  float4 ce = cen4[myE], cj = cen4[sj];
  float ddx = ce.x - cj.x, ddy = ce.y - cj.y, ddz = ce.z - cj.z;
  const float sdist = sqrtf(ddx*ddx + ddy*ddy + ddz*ddz);
  const float sincut = (sdist <= CUTF) ? 1.0f : 0.0f;
  if (sb == 0) { sDot[srow] = dt; sDist[srow] = sdist; }
  {
    u16 tmp[16];
    #pragma unroll
    for (int i4 = 0; i4 < 4; ++i4) {
      float4 cc = *(const float4*)(centers + sb*16 + i4*4);
      float4 ww = *(const float4*)(widths  + sb*16 + i4*4);
      float c4v[4] = {cc.x,cc.y,cc.z,cc.w}, w4[4] = {ww.x,ww.y,ww.z,ww.w};
      #pragma unroll
      for (int jj = 0; jj < 4; ++jj) {
        float df = sdist - c4v[jj];
        tmp[i4*4+jj] = f2bf(__expf(-w4[jj]*df*df) * sincut);
      }
    }
    #pragma unroll
    for (int gg = 0; gg < 2; ++gg) {
      u16x8 vv;
      #pragma unroll
      for (int jj = 0; jj < 8; ++jj) vv[jj] = tmp[gg*8+jj];
      int widx = (srow*64 + sb*16 + gg*8) ^ ((srow & 7) << 3);
      *(u16x8*)(&sA[widx]) = vv;
    }
  }
  {
    const int qe = eperm[gb + (t >> 7)];
    sQW[t >> 7][t & 127] = qW1[(size_t)qe*HID + (t & 127)];
  }
  if (t < 128) sIdx[t] = idx[eperm[gb + (t >> 5)]*KNB + (t & 31)];

  // ---- LAST loads of the phase: vfb prefetch for the combine tail ----
  u32 vp[16];
  {
    const int pe = eperm[gb + (t >> 7)];
    const int colp = t & 127;
    #pragma unroll
    for (int kk = 0; kk < 16; ++kk) {
      int j0 = idx[pe*KNB + 2*kk], j1 = idx[pe*KNB + 2*kk + 1];
      u32 a = vfb[(size_t)j0*HID + colp];
      u32 b = vfb[(size_t)j1*HID + colp];
      vp[kk] = a | (b << 16);
    }
  }
  __syncthreads();

  f32x4 acc[4][2];
  #pragma unroll
  for (int rt = 0; rt < 4; ++rt)
    #pragma unroll
    for (int ct = 0; ct < 2; ++ct) acc[rt][ct] = (f32x4){0.f,0.f,0.f,0.f};

  // ---- GEMM1: rbf (K=64) ----
  #pragma unroll
  for (int ks = 0; ks < 2; ++ks) {
    bf16x8 af[4], bfr[2];
    #pragma unroll
    for (int rt = 0; rt < 4; ++rt) {
      int row = rh*64 + rt*16 + l15;
      int aidx = (row*64 + ks*32 + l4*8) ^ ((row & 7) << 3);
      af[rt] = *(const bf16x8*)(&sA[aidx]);
    }
    #pragma unroll
    for (int ct = 0; ct < 2; ++ct) {
      int col = c4*32 + ct*16 + l15;
      bfr[ct] = *(const bf16x8*)(&Wt1r[col*64 + ks*32 + l4*8]);
    }
    #pragma unroll
    for (int rt = 0; rt < 4; ++rt)
      #pragma unroll
      for (int ct = 0; ct < 2; ++ct)
        acc[rt][ct] = __builtin_amdgcn_mfma_f32_16x16x32_bf16(af[rt], bfr[ct], acc[rt][ct], 0, 0, 0);
  }

  // ---- epilogue 1: x = acc + qW1[e] + kW1[j](sH in-place) + dot*w320; silu -> sH ----
  {
    float w320[2];
    #pragma unroll
    for (int ct = 0; ct < 2; ++ct) {
      int col = c4*32 + ct*16 + l15;
      w320[ct] = W1[320*HID + col];
    }
    #pragma unroll
    for (int rt = 0; rt < 4; ++rt) {
      #pragma unroll
      for (int r = 0; r < 4; ++r) {
        int row = rh*64 + rt*16 + l4*4 + r;
        float dv = sDot[row];
        int eh = row >> 5;
        #pragma unroll
        for (int ct = 0; ct < 2; ++ct) {
          int col = c4*32 + ct*16 + l15;
          int hidx = (row*128 + col) ^ ((row & 7) << 3);
          float x = acc[rt][ct][r] + sQW[eh][col] + bf2f(sH[hidx]) + dv*w320[ct];
          float h = x / (1.0f + __expf(-x));
          sH[hidx] = f2bf(h);
        }
      }
    }
  }
  __syncthreads();            // all GEMM1 sA reads done; sA alias region now usable

  #pragma unroll
  for (int rt = 0; rt < 4; ++rt)
    #pragma unroll
    for (int ct = 0; ct < 2; ++ct) acc[rt][ct] = (f32x4){0.f,0.f,0.f,0.f};

  // ---- GEMM2: h @ W2 ----
  #pragma unroll
  for (int ks = 0; ks < 4; ++ks) {
    bf16x8 af[4], bfr[2];
    #pragma unroll
    for (int rt = 0; rt < 4; ++rt) {
      int row = rh*64 + rt*16 + l15;
      int aidx = (row*128 + ks*32 + l4*8) ^ ((row & 7) << 3);
      af[rt] = *(const bf16x8*)(&sH[aidx]);
    }
    #pragma unroll
    for (int ct = 0; ct < 2; ++ct) {
      int col = c4*32 + ct*16 + l15;
      bfr[ct] = *(const bf16x8*)(&Wt2[col*128 + ks*32 + l4*8]);
    }
    #pragma unroll
    for (int rt = 0; rt < 4; ++rt)
      #pragma unroll
      for (int ct = 0; ct < 2; ++ct)
        acc[rt][ct] = __builtin_amdgcn_mfma_f32_16x16x32_bf16(af[rt], bfr[ct], acc[rt][ct], 0, 0, 0);
  }

  // ---- epilogue 2: silu, dot W3, reduce over this wave's 32 cols -> spart ----
  {
    float b2r[2], w3r[2];
    #pragma unroll
    for (int ct = 0; ct < 2; ++ct) {
      int col = c4*32 + ct*16 + l15;
      b2r[ct] = b2[col]; w3r[ct] = W3[col];
    }
    #pragma unroll
    for (int rt = 0; rt < 4; ++rt) {
      #pragma unroll
      for (int r = 0; r < 4; ++r) {
        float part = 0.f;
        #pragma unroll
        for (int ct = 0; ct < 2; ++ct) {
          float x = acc[rt][ct][r] + b2r[ct];
          float h = x / (1.0f + __expf(-x));
          part = fmaf(h, w3r[ct], part);
        }
        part += __shfl_xor(part, 1, 64);
        part += __shfl_xor(part, 2, 64);
        part += __shfl_xor(part, 4, 64);
        part += __shfl_xor(part, 8, 64);
        if (l15 == 0) spart[c4*128 + rh*64 + rt*16 + l4*4 + r] = part;
      }
    }
  }
  __syncthreads();

  // ---- softmax + coord update: wave w (<4) -> edge w ----
  if (w < 4 && l < 32) {
    const int eh = w;
    const int row = eh*32 + l;
    float raw = spart[row] + spart[128 + row] + spart[256 + row] + spart[384 + row] + b3[0];
    float sc = (sDist[row] <= CUTF) ? raw : 0.0f;
    float m = sc;
    #pragma unroll
    for (int mm = 1; mm < 32; mm <<= 1) m = fmaxf(m, __shfl_xor(m, mm, 64));
    m = fmaxf(m, 0.0f);
    float ex = __expf(sc - m);
    float Z = ex;
    #pragma unroll
    for (int mm = 1; mm < 32; mm <<= 1) Z += __shfl_xor(Z, mm, 64);
    Z += 8160.0f * __expf(-m);               // (E-K) zero-score tail
    float wv = ex / Z;
    swk[eh*32 + l] = wv;
    int e = sEid[eh];
    int j = sIdx[row];
    float g2 = wv * gates[j];
    float4 cee = cen4[e], cjj = cen4[j];
    float cx = g2*(cee.x - cjj.x), cy = g2*(cee.y - cjj.y), cz = g2*(cee.z - cjj.z);
    #pragma unroll
    for (int mm = 1; mm < 32; mm <<= 1) {
      cx += __shfl_xor(cx, mm, 64);
      cy += __shfl_xor(cy, mm, 64);
      cz += __shfl_xor(cz, mm, 64);
    }
    if (l == 0) {
      outc[e*3+0] = ec[e*3+0] + cx;
      outc[e*3+1] = ec[e*3+1] + cy;
      outc[e*3+2] = ec[e*3+2] + cz;
    }
  }
  __syncthreads();

  // ---- weighted V (prefetched regs) + residual -> sUpd ----
  {
    const int eh = t >> 7, col = t & 127;
    float acc2 = 0.f;
    #pragma unroll
    for (int kk = 0; kk < 16; ++kk) {
      acc2 = fmaf(swk[eh*32 + 2*kk],     bf2f((u16)(vp[kk] & 0xffffu)), acc2);
      acc2 = fmaf(swk[eh*32 + 2*kk + 1], bf2f((u16)(vp[kk] >> 16)),     acc2);
    }
    sUpd[eh*128 + col] = ef[(size_t)sEid[eh]*HID + col] + acc2;
  }
  __syncthreads();

  // ---- Wo GEMV + residual + LayerNorm ----
  {
    const int eh = t >> 7, o = t & 127;
    const int e = sEid[eh];
    float accw = 0.f;
    #pragma unroll 8
    for (int d = 0; d < 128; ++d)
      accw = fmaf(sUpd[eh*128 + d], Wo[d*128 + o], accw);
    float x = ef[(size_t)e*HID + o] + accw + bo[o];
    float s1 = x, s2 = x*x;
    #pragma unroll
    for (int m = 1; m < 64; m <<= 1) {
      s1 += __shfl_xor(s1, m, 64);
      s2 += __shfl_xor(s2, m, 64);
    }
    if (l == 0) { sred[w*2+0] = s1; sred[w*2+1] = s2; }
    __syncthreads();
    float t1 = sred[(eh*2)*2+0] + sred[(eh*2+1)*2+0];
    float t2 = sred[(eh*2)*2+1] + sred[(eh*2+1)*2+1];
    float mu = t1 * (1.0f/128.0f);
    float var = t2 * (1.0f/128.0f) - mu*mu;
    float rs = rsqrtf(var + LNEPS);
    outf[(size_t)e*HID + o] = (x - mu)*rs*gamma[o] + beta[o];
  }
}

extern "C" void kernel_launch(void* const* d_in, const int* in_sizes, int n_in,
                              void* d_out, int out_size, void* d_ws, size_t ws_size,
                              hipStream_t stream) {
  const float* ef   = (const float*)d_in[0];
  const float* ec   = (const float*)d_in[1];
  const float* nc   = (const float*)d_in[2];
  const float* Wq   = (const float*)d_in[3];
  const float* Wk   = (const float*)d_in[4];
  const float* Wv   = (const float*)d_in[5];
  const float* W1   = (const float*)d_in[6];
  const float* b1   = (const float*)d_in[7];
  const float* W2   = (const float*)d_in[8];
  const float* b2   = (const float*)d_in[9];
  const float* W3   = (const float*)d_in[10];
  const float* b3   = (const float*)d_in[11];
  const float* Wg1  = (const float*)d_in[12];
  const float* bg1  = (const float*)d_in[13];
  const float* Wg2  = (const float*)d_in[14];
  const float* bg2  = (const float*)d_in[15];
  const float* Wo   = (const float*)d_in[16];
  const float* bo   = (const float*)d_in[17];
  const float* gamma= (const float*)d_in[18];
  const float* beta = (const float*)d_in[19];
  const float* centers = (const float*)d_in[20];
  const float* widths  = (const float*)d_in[21];
  const int*   eidx    = (const int*)d_in[22];

  float* outf = (float*)d_out;
  float* outc = outf + (size_t)E_N * HID;

  // workspace layout (16B-aligned chunks first)
  float4* cen4 = (float4*)d_ws;                        // 8192 * 16B
  u16*   kjp   = (u16*)(cen4 + E_N);                   // E * 256 bf16 (4 MB)
  u16*   vfb   = kjp + (size_t)E_N*256;                // E * 128 bf16 (2 MB)
  u16*   Wt1r  = vfb + (size_t)E_N*128;                // 128*64 bf16
  u16*   Wt2   = Wt1r + 128*64;                        // 128*128 bf16
  u16*   Wqt   = Wt2  + 128*128;
  u16*   Wkt   = Wqt  + 128*128;
  u16*   Wvt   = Wkt  + 128*128;
  u16*   Wqct  = Wvt  + 128*128;
  u16*   Wkct  = Wqct + 128*128;
  u16*   Wvgt  = Wkct + 128*128;
  int*   idx   = (int*)(Wvgt + 128*128);
  int*   eperm = idx + E_N*KNB;                        // 8192 ints
  float* qf    = (float*)(eperm + E_N);
  float* qW1   = qf + (size_t)E_N*HID;
  float* gates = qW1 + (size_t)E_N*HID;

  k_pre<<<672, 256, 0, stream>>>(W1, W2, Wq, Wk, Wv, Wg1, nc, eidx,
                                 Wt1r, Wt2, Wqt, Wkt, Wvt, Wqct, Wkct, Wvgt, cen4);
  k_sort<<<1, 256, 0, stream>>>(cen4, eperm);
  k_topk<<<E_N/8, 256, 0, stream>>>(cen4, idx);
  k_qkv<<<E_N/32, 256, 0, stream>>>(ef, Wqt, Wkt, Wvt, Wqct, Wkct, Wvgt,
                                    b1, bg1, Wg2, bg2, qf, qW1, kjp, vfb, gates);
  k_mega<<<E_N*KNB/128, 512, 0, stream>>>(idx, eperm, qf, cen4, qW1, kjp, vfb, gates,
                                          Wt1r, Wt2, W1, b2, W3, b3, centers, widths,
                                          ef, ec, Wo, bo, gamma, beta, outf, outc);
}

// Round 18
// 187.233 us; speedup vs baseline: 1.1222x; 1.1222x over previous
//
#include <hip/hip_runtime.h>
#include <math.h>

#define E_N   8192
#define HID   128
#define NRAD  64
#define KNB   32
#define CUTF  10.0f
#define LNEPS 1e-5f

typedef unsigned short u16;
typedef unsigned int   u32;
typedef unsigned long long u64;
typedef __bf16 bf16x8 __attribute__((ext_vector_type(8)));
typedef u16    u16x8  __attribute__((ext_vector_type(8)));
typedef float  f32x4  __attribute__((ext_vector_type(4)));

__device__ __forceinline__ u16 f2bf(float f) {          // native HW cvt (RNE)
  __bf16 h = (__bf16)f;
  return __builtin_bit_cast(u16, h);
}
__device__ __forceinline__ float bf2f(u16 v) {
  return __uint_as_float(((u32)v) << 16);
}

__device__ __forceinline__ u64 shflx64(u64 v, int m) {
  int lo = __shfl_xor((int)(v & 0xffffffffull), m, 64);
  int hi = __shfl_xor((int)(v >> 32), m, 64);
  return ((u64)(unsigned)hi << 32) | (unsigned)lo;
}

// monotone-u32 key of squared distance; fmaf-pinned so pass1/pass2 agree bitwise
__device__ __forceinline__ u32 d2key(const float4 me, const float4 c) {
  float dot = fmaf(me.x, c.x, fmaf(me.y, c.y, me.z * c.z));
  float d2  = fmaf(-2.0f, dot, me.w + c.w);     // gram trick, as in reference
  u32 u = __float_as_uint(d2);
  return u ^ (((u32)((int)u >> 31)) | 0x80000000u);
}

// ---------------- kernel 0: merged prep (bf16 panels / fused products / centers) ----------------
__global__ __launch_bounds__(256) void k_pre(
    const float* __restrict__ W1, const float* __restrict__ W2,
    const float* __restrict__ Wq, const float* __restrict__ Wk,
    const float* __restrict__ Wv, const float* __restrict__ Wg1,
    const float* __restrict__ Wo,
    const float* __restrict__ nc, const int* __restrict__ ei,
    u16* __restrict__ Wt1r, u16* __restrict__ Wt2,
    u16* __restrict__ Wqt, u16* __restrict__ Wkt, u16* __restrict__ Wvt,
    u16* __restrict__ Wqct, u16* __restrict__ Wkct, u16* __restrict__ Wvgt,
    u16* __restrict__ Wot,
    float4* __restrict__ cen4) {
  const int b = blockIdx.x, t = threadIdx.x;
  if (b < 128) {
    if (t < 64)       Wt1r[b*64 + t]      = f2bf(W1[(256+t)*HID + b]);   // rbf rows 256..319
    else if (t < 192) Wt2[b*HID + (t-64)] = f2bf(W2[(t-64)*HID + b]);
  } else if (b < 256) {
    const int r = b - 128, o = t & 127;
    float a = 0.f;
    if (t < 128) {
      #pragma unroll 8
      for (int m = 0; m < 128; ++m) a = fmaf(Wq[r*128+m], W1[m*128+o], a);
      Wqct[o*128 + r] = f2bf(a);
    } else {
      #pragma unroll 8
      for (int m = 0; m < 128; ++m) a = fmaf(Wk[r*128+m], W1[(128+m)*128+o], a);
      Wkct[o*128 + r] = f2bf(a);
    }
  } else if (b < 384) {
    const int r = b - 256;
    if (t < 128) {
      float a = 0.f;
      #pragma unroll 8
      for (int m = 0; m < 128; ++m) a = fmaf(Wv[r*128+m], Wg1[m*128+t], a);
      Wvgt[t*128 + r] = f2bf(a);
    }
  } else if (b < 512) {
    const int c = b - 384;
    if (t < 128) Wqt[c*128 + t]       = f2bf(Wq[t*128 + c]);
    else         Wkt[c*128 + (t-128)] = f2bf(Wk[(t-128)*128 + c]);
  } else if (b < 640) {
    const int c = b - 512;
    if (t < 128) Wvt[c*128 + t]       = f2bf(Wv[t*128 + c]);
    else         Wot[c*128 + (t-128)] = f2bf(Wo[(t-128)*128 + c]);
  } else {
    const int e = (b - 640)*256 + t;
    if (e < E_N) {
      int a = ei[e], bb = ei[E_N + e];
      float x = (nc[a*3+0] + nc[bb*3+0]) * 0.5f;
      float y = (nc[a*3+1] + nc[bb*3+1]) * 0.5f;
      float z = (nc[a*3+2] + nc[bb*3+2]) * 0.5f;
      cen4[e] = make_float4(x, y, z, x*x + y*y + z*z);
    }
  }
}

// ---------------- kernel 2: top-K, 8 rows/block, two-pass prune + exact lex rank ----------------
__global__ __launch_bounds__(256) void k_topk(const float4* __restrict__ cen4,
                                              int* __restrict__ idxo) {
  const int row0 = blockIdx.x * 8;
  const int t = threadIdx.x;
  const int lane = t & 63, w = t >> 6;
  __shared__ __align__(16) u32 smin[8][256];   // 8 KiB
  __shared__ __align__(16) u64 comp[2048];     // 16 KiB survivor buffer
  __shared__ u32 sU[8];
  __shared__ u32 scnt, scnt_r[8];
  __shared__ u64 wred[4];
  __shared__ u64 winner;

  if (t == 0) scnt = 0;
  if (t < 8) scnt_r[t] = 0;

  float4 me[8];
  #pragma unroll
  for (int r = 0; r < 8; ++r) me[r] = cen4[row0 + r];

  // ---- pass 1: running mins for 8 rows ----
  u32 mn[8];
  #pragma unroll
  for (int r = 0; r < 8; ++r) mn[r] = 0xFFFFFFFFu;
  for (int s = 0; s < 32; ++s) {
    float4 c = cen4[t + (s << 8)];
    #pragma unroll
    for (int r = 0; r < 8; ++r) {
      u32 k = d2key(me[r], c);
      mn[r] = k < mn[r] ? k : mn[r];
    }
  }
  #pragma unroll
  for (int r = 0; r < 8; ++r) smin[r][t] = mn[r];
  __syncthreads();

  // ---- per-row bound: wave w handles rows 2w, 2w+1; in-wave radix bisect ----
  #pragma unroll
  for (int rr = 0; rr < 2; ++rr) {
    const int r = w*2 + rr;
    uint4 vv = *(const uint4*)&smin[r][lane*4];
    u32 P = 0;
    u32 rem = 31;
    #pragma unroll 1
    for (int b = 31; b >= 12; --b) {
      u32 bit = 1u << b;
      bool pm0 = ((u64)(vv.x ^ P) >> (b+1)) == 0ull;
      bool pm1 = ((u64)(vv.y ^ P) >> (b+1)) == 0ull;
      bool pm2 = ((u64)(vv.z ^ P) >> (b+1)) == 0ull;
      bool pm3 = ((u64)(vv.w ^ P) >> (b+1)) == 0ull;
      u32 c0 = (u32)__popcll(__ballot(pm0 && !(vv.x & bit)))
             + (u32)__popcll(__ballot(pm1 && !(vv.y & bit)))
             + (u32)__popcll(__ballot(pm2 && !(vv.z & bit)))
             + (u32)__popcll(__ballot(pm3 && !(vv.w & bit)));
      if (rem >= c0) { P |= bit; rem -= c0; }
    }
    if (lane == 0) sU[r] = P | 0xFFFu;
  }
  __syncthreads();

  // ---- pass 2: recompute keys, compact survivors ----
  u32 Ur[8];
  #pragma unroll
  for (int r = 0; r < 8; ++r) Ur[r] = sU[r];
  for (int s = 0; s < 32; ++s) {
    float4 c = cen4[t + (s << 8)];
    #pragma unroll
    for (int r = 0; r < 8; ++r) {
      u32 k = d2key(me[r], c);
      if (k <= Ur[r]) {
        u32 pos = atomicAdd(&scnt, 1u);
        atomicAdd(&scnt_r[r], 1u);
        if (pos < 2048u)
          comp[pos] = ((u64)r << 45) | (((u64)k) << 13) | (u32)(t + (s << 8));
      }
    }
  }
  __syncthreads();
  const int cnt = (int)scnt;

  if (cnt <= 2048) {
    u32 off[8];
    off[0] = 0;
    #pragma unroll
    for (int r = 1; r < 8; ++r) off[r] = off[r-1] + scnt_r[r-1];
    for (int i = t; i < cnt; i += 256) {
      u64 mev = comp[i];
      int rk = 0;
      int j2 = 0;
      for (; j2 + 2 <= cnt; j2 += 2) {
        ulonglong2 pr = *(const ulonglong2*)&comp[j2];
        rk += (pr.x < mev) ? 1 : 0;
        rk += (pr.y < mev) ? 1 : 0;
      }
      if (j2 < cnt) rk += (comp[j2] < mev) ? 1 : 0;
      int r = (int)(mev >> 45);
      int rank = rk - (int)off[r];
      if (rank < KNB) idxo[(row0 + r)*KNB + rank] = (int)(mev & 0x1FFFull);
    }
  } else {
    // overflow fallback (never taken statistically): exact per-row extract-min
    for (int r = 0; r < 8; ++r) {
      float4 mer = cen4[row0 + r];
      u32 taken = 0;
      for (int kk2 = 0; kk2 < KNB; ++kk2) {
        u64 lk = 0xFFFFFFFFFFFFFFFFull;
        for (int s = 0; s < 32; ++s) {
          if (taken & (1u << s)) continue;
          float4 c = cen4[t + (s << 8)];
          u64 kx = (((u64)d2key(mer, c)) << 13) | (u32)(t + (s << 8));
          lk = kx < lk ? kx : lk;
        }
        #pragma unroll
        for (int m = 1; m < 64; m <<= 1) {
          u64 o = shflx64(lk, m);
          lk = o < lk ? o : lk;
        }
        if (lane == 0) wred[w] = lk;
        __syncthreads();
        if (t == 0) {
          u64 w0 = wred[0] < wred[1] ? wred[0] : wred[1];
          u64 w1 = wred[2] < wred[3] ? wred[2] : wred[3];
          winner = w0 < w1 ? w0 : w1;
          idxo[(row0 + r)*KNB + kk2] = (int)(winner & 0x1FFFull);
        }
        __syncthreads();
        u64 jw = winner & 0x1FFFull;
        if (((u32)jw & 255u) == (u32)t) taken |= 1u << ((u32)jw >> 8);
        __syncthreads();
      }
    }
  }
}

// ---------------- kernel 3: 6-panel MFMA projections, 32 edges/block ----------------
__global__ __launch_bounds__(256) void k_qkv(const float* __restrict__ ef,
    const u16* __restrict__ Wqt, const u16* __restrict__ Wkt, const u16* __restrict__ Wvt,
    const u16* __restrict__ Wqct, const u16* __restrict__ Wkct, const u16* __restrict__ Wvgt,
    const float* __restrict__ b1, const float* __restrict__ bg1,
    const float* __restrict__ Wg2, const float* __restrict__ bg2,
    float* __restrict__ qf, float* __restrict__ qW1,
    u16* __restrict__ kjp, u16* __restrict__ vfb, float* __restrict__ gates) {
  __shared__ u16 sE[32*128];      // ef tile bf16, swizzled (8 KiB)
  __shared__ float spart[4][32];
  const int t = threadIdx.x;
  const int w = t >> 6, l = t & 63;
  const int l15 = l & 15, l4 = l >> 4;
  const int e0 = blockIdx.x * 32;
  const int colw = w * 32;

  // stage ef tile
  {
    const int srow = t >> 3, sb = t & 7;
    const float4* src = (const float4*)(ef + (size_t)(e0 + srow)*HID + sb*16);
    #pragma unroll
    for (int g = 0; g < 2; ++g) {
      float4 v0 = src[g*2], v1 = src[g*2+1];
      u16x8 vv;
      vv[0]=f2bf(v0.x); vv[1]=f2bf(v0.y); vv[2]=f2bf(v0.z); vv[3]=f2bf(v0.w);
      vv[4]=f2bf(v1.x); vv[5]=f2bf(v1.y); vv[6]=f2bf(v1.z); vv[7]=f2bf(v1.w);
      int widx = (srow*128 + sb*16 + g*8) ^ ((srow & 7) << 3);
      *(u16x8*)(&sE[widx]) = vv;
    }
  }
  __syncthreads();

  // preload all A fragments (2 row-tiles x 4 k-slices)
  bf16x8 afq[2][4];
  #pragma unroll
  for (int rt = 0; rt < 2; ++rt) {
    int row = rt*16 + l15;
    #pragma unroll
    for (int ks = 0; ks < 4; ++ks) {
      int aidx = (row*128 + ks*32 + l4*8) ^ ((row & 7) << 3);
      afq[rt][ks] = *(const bf16x8*)(&sE[aidx]);
    }
  }

  f32x4 a2[2][2];
  auto gemm_panel = [&](const u16* __restrict__ P) {
    #pragma unroll
    for (int rt = 0; rt < 2; ++rt)
      #pragma unroll
      for (int ct = 0; ct < 2; ++ct) a2[rt][ct] = (f32x4){0.f,0.f,0.f,0.f};
    #pragma unroll
    for (int ks = 0; ks < 4; ++ks) {
      bf16x8 bfr[2];
      #pragma unroll
      for (int ct = 0; ct < 2; ++ct)
        bfr[ct] = *(const bf16x8*)(&P[(colw + ct*16 + l15)*128 + ks*32 + l4*8]);
      #pragma unroll
      for (int rt = 0; rt < 2; ++rt)
        #pragma unroll
        for (int ct = 0; ct < 2; ++ct)
          a2[rt][ct] = __builtin_amdgcn_mfma_f32_16x16x32_bf16(afq[rt][ks], bfr[ct], a2[rt][ct], 0, 0, 0);
    }
  };

  // q
  gemm_panel(Wqt);
  #pragma unroll
  for (int rt = 0; rt < 2; ++rt)
    #pragma unroll
    for (int r = 0; r < 4; ++r) {
      size_t e = e0 + rt*16 + l4*4 + r;
      #pragma unroll
      for (int ct = 0; ct < 2; ++ct)
        qf[e*HID + colw + ct*16 + l15] = a2[rt][ct][r];
    }
  // k
  gemm_panel(Wkt);
  #pragma unroll
  for (int rt = 0; rt < 2; ++rt)
    #pragma unroll
    for (int r = 0; r < 4; ++r) {
      size_t e = e0 + rt*16 + l4*4 + r;
      #pragma unroll
      for (int ct = 0; ct < 2; ++ct)
        kjp[e*256 + 128 + colw + ct*16 + l15] = f2bf(a2[rt][ct][r]);
    }
  // v
  gemm_panel(Wvt);
  #pragma unroll
  for (int rt = 0; rt < 2; ++rt)
    #pragma unroll
    for (int r = 0; r < 4; ++r) {
      size_t e = e0 + rt*16 + l4*4 + r;
      #pragma unroll
      for (int ct = 0; ct < 2; ++ct)
        vfb[e*HID + colw + ct*16 + l15] = f2bf(a2[rt][ct][r]);
    }
  // qW1 = ef@(Wq@W1q) + b1
  gemm_panel(Wqct);
  {
    float b1r[2];
    #pragma unroll
    for (int ct = 0; ct < 2; ++ct) b1r[ct] = b1[colw + ct*16 + l15];
    #pragma unroll
    for (int rt = 0; rt < 2; ++rt)
      #pragma unroll
      for (int r = 0; r < 4; ++r) {
        size_t e = e0 + rt*16 + l4*4 + r;
        #pragma unroll
        for (int ct = 0; ct < 2; ++ct)
          qW1[e*HID + colw + ct*16 + l15] = a2[rt][ct][r] + b1r[ct];
      }
  }
  // kW1 = ef@(Wk@W1k)
  gemm_panel(Wkct);
  #pragma unroll
  for (int rt = 0; rt < 2; ++rt)
    #pragma unroll
    for (int r = 0; r < 4; ++r) {
      size_t e = e0 + rt*16 + l4*4 + r;
      #pragma unroll
      for (int ct = 0; ct < 2; ++ct)
        kjp[e*256 + colw + ct*16 + l15] = f2bf(a2[rt][ct][r]);
    }
  // gates: g1 = silu(ef@(Wv@Wg1) + bg1); gate = sigmoid(g1.Wg2 + bg2)
  gemm_panel(Wvgt);
  {
    float bgr[2], w3r[2];
    #pragma unroll
    for (int ct = 0; ct < 2; ++ct) {
      int col = colw + ct*16 + l15;
      bgr[ct] = bg1[col]; w3r[ct] = Wg2[col];
    }
    #pragma unroll
    for (int rt = 0; rt < 2; ++rt)
      #pragma unroll
      for (int r = 0; r < 4; ++r) {
        float part = 0.f;
        #pragma unroll
        for (int ct = 0; ct < 2; ++ct) {
          float x = a2[rt][ct][r] + bgr[ct];
          float g = x / (1.0f + __expf(-x));
          part = fmaf(g, w3r[ct], part);
        }
        part += __shfl_xor(part, 1, 64);
        part += __shfl_xor(part, 2, 64);
        part += __shfl_xor(part, 4, 64);
        part += __shfl_xor(part, 8, 64);
        if (l15 == 0) spart[w][rt*16 + l4*4 + r] = part;
      }
  }
  __syncthreads();
  if (t < 32)
    gates[e0 + t] = 1.0f / (1.0f + __expf(-(spart[0][t] + spart[1][t] + spart[2][t] + spart[3][t] + bg2[0])));
}

// ---------------- kernel 5: mega (MLP + softmax + combine + Wo-MFMA + LayerNorm), 4 edges/block ----------------
__global__ __launch_bounds__(512) void k_mega(
    const int* __restrict__ idx,
    const float* __restrict__ qf,
    const float4* __restrict__ cen4,
    const float* __restrict__ qW1, const u16* __restrict__ kjp,
    const u16* __restrict__ vfb, const float* __restrict__ gates,
    const u16* __restrict__ Wt1r, const u16* __restrict__ Wt2,
    const u16* __restrict__ Wot,
    const float* __restrict__ W1,
    const float* __restrict__ b2, const float* __restrict__ W3,
    const float* __restrict__ b3,
    const float* __restrict__ centers, const float* __restrict__ widths,
    const float* __restrict__ ef, const float* __restrict__ ec,
    const float* __restrict__ bo,
    const float* __restrict__ gamma, const float* __restrict__ beta,
    float* __restrict__ outf, float* __restrict__ outc) {
  __shared__ u16 sH[128*128];     // 32 KiB: kW1[j] tile -> in-place h tile
  __shared__ u16 sA[128*64];      // 16 KiB: rbf tile; aliased after GEMM1 drain:
  float* spart = (float*)sA;            // [4][128] col-slab partial scores (f32 0..511)
  float* swk   = (float*)sA + 512;      // [4][32]  softmax weights        (512..639)
  float* sred  = (float*)sA + 640;      // [8][2]   LN partial sums        (640..655)
  float* sWo   = (float*)sA + 656;      // [4][128] Wo-MFMA output         (656..1167)
  u16*   sUB   = (u16*)((float*)sA + 1168); // [16][128] bf16 upd tile (rows 4-15 garbage)
  __shared__ float sQW[4][128];   // 2 KiB
  __shared__ float sDot[128];
  __shared__ float sDist[128];
  __shared__ int   sIdx[128];

  const int t  = threadIdx.x;
  const int w  = t >> 6, l = t & 63;
  const int l15 = l & 15, l4 = l >> 4;
  const int c4 = w & 3, rh = w >> 2;
  const int rowbase = blockIdx.x * 128;
  const int eBase = rowbase >> 5;           // four edges per block

  // ---- stage: kW1[j] tile (vectorized gather -> sH), dot, dist, rbf -> sA ----
  const int srow = t >> 2, sb = t & 3;      // 128 rows x 4 threads
  const int sp = rowbase + srow;
  const int se = sp >> 5;
  const int sj = idx[sp];
  {
    const u16x8* kw = (const u16x8*)(kjp + (size_t)sj*256 + sb*32);
    #pragma unroll
    for (int g = 0; g < 4; ++g) {
      int widx = (srow*128 + sb*32 + g*8) ^ ((srow & 7) << 3);
      *(u16x8*)(&sH[widx]) = kw[g];
    }
  }
  // q.k dot: q f32 x k bf16 (packed row), 4 lanes/row
  const u16x8* kb = (const u16x8*)(kjp + (size_t)sj*256 + 128 + sb*32);
  const float4* q4 = (const float4*)(qf + (size_t)se*HID) + sb*8;
  float dt = 0.f;
  #pragma unroll
  for (int i = 0; i < 4; ++i) {
    u16x8 kv8 = kb[i];
    float4 qa = q4[i*2], qb = q4[i*2+1];
    dt += bf2f(kv8[0])*qa.x + bf2f(kv8[1])*qa.y + bf2f(kv8[2])*qa.z + bf2f(kv8[3])*qa.w
        + bf2f(kv8[4])*qb.x + bf2f(kv8[5])*qb.y + bf2f(kv8[6])*qb.z + bf2f(kv8[7])*qb.w;
  }
  dt += __shfl_xor(dt, 1, 64);
  dt += __shfl_xor(dt, 2, 64);
  // geometry
  float4 ce = cen4[se], cj = cen4[sj];
  float ddx = ce.x - cj.x, ddy = ce.y - cj.y, ddz = ce.z - cj.z;
  const float sdist = sqrtf(ddx*ddx + ddy*ddy + ddz*ddz);
  const float sincut = (sdist <= CUTF) ? 1.0f : 0.0f;
  if (sb == 0) { sDot[srow] = dt; sDist[srow] = sdist; }
  {
    u16 tmp[16];
    #pragma unroll
    for (int i4 = 0; i4 < 4; ++i4) {
      float4 cc = *(const float4*)(centers + sb*16 + i4*4);
      float4 ww = *(const float4*)(widths  + sb*16 + i4*4);
      float c4v[4] = {cc.x,cc.y,cc.z,cc.w}, w4[4] = {ww.x,ww.y,ww.z,ww.w};
      #pragma unroll
      for (int jj = 0; jj < 4; ++jj) {
        float df = sdist - c4v[jj];
        tmp[i4*4+jj] = f2bf(__expf(-w4[jj]*df*df) * sincut);
      }
    }
    #pragma unroll
    for (int g = 0; g < 2; ++g) {
      u16x8 vv;
      #pragma unroll
      for (int jj = 0; jj < 8; ++jj) vv[jj] = tmp[g*8+jj];
      int widx = (srow*64 + sb*16 + g*8) ^ ((srow & 7) << 3);
      *(u16x8*)(&sA[widx]) = vv;
    }
  }
  sQW[t >> 7][t & 127] = qW1[(size_t)(eBase + (t >> 7))*HID + (t & 127)];
  if (t < 128) sIdx[t] = idx[rowbase + t];

  // ---- LAST loads of the phase: vfb prefetch for the combine tail ----
  u32 vp[16];
  {
    const int eh2 = t >> 7, colp = t & 127;
    const int ib = rowbase + eh2*32;
    #pragma unroll
    for (int kk = 0; kk < 16; ++kk) {
      int j0 = idx[ib + 2*kk], j1 = idx[ib + 2*kk + 1];
      u32 a = vfb[(size_t)j0*HID + colp];
      u32 b = vfb[(size_t)j1*HID + colp];
      vp[kk] = a | (b << 16);
    }
  }
  __syncthreads();

  f32x4 acc[4][2];
  #pragma unroll
  for (int rt = 0; rt < 4; ++rt)
    #pragma unroll
    for (int ct = 0; ct < 2; ++ct) acc[rt][ct] = (f32x4){0.f,0.f,0.f,0.f};

  // ---- GEMM1: rbf (K=64) ----
  #pragma unroll
  for (int ks = 0; ks < 2; ++ks) {
    bf16x8 af[4], bfr[2];
    #pragma unroll
    for (int rt = 0; rt < 4; ++rt) {
      int row = rh*64 + rt*16 + l15;
      int aidx = (row*64 + ks*32 + l4*8) ^ ((row & 7) << 3);
      af[rt] = *(const bf16x8*)(&sA[aidx]);
    }
    #pragma unroll
    for (int ct = 0; ct < 2; ++ct) {
      int col = c4*32 + ct*16 + l15;
      bfr[ct] = *(const bf16x8*)(&Wt1r[col*64 + ks*32 + l4*8]);
    }
    #pragma unroll
    for (int rt = 0; rt < 4; ++rt)
      #pragma unroll
      for (int ct = 0; ct < 2; ++ct)
        acc[rt][ct] = __builtin_amdgcn_mfma_f32_16x16x32_bf16(af[rt], bfr[ct], acc[rt][ct], 0, 0, 0);
  }

  // ---- epilogue 1: x = acc + qW1[e] + kW1[j](sH in-place) + dot*w320; silu -> sH ----
  {
    float w320[2];
    #pragma unroll
    for (int ct = 0; ct < 2; ++ct) {
      int col = c4*32 + ct*16 + l15;
      w320[ct] = W1[320*HID + col];
    }
    #pragma unroll
    for (int rt = 0; rt < 4; ++rt) {
      #pragma unroll
      for (int r = 0; r < 4; ++r) {
        int row = rh*64 + rt*16 + l4*4 + r;
        float dv = sDot[row];
        int eh = row >> 5;
        #pragma unroll
        for (int ct = 0; ct < 2; ++ct) {
          int col = c4*32 + ct*16 + l15;
          int hidx = (row*128 + col) ^ ((row & 7) << 3);
          float x = acc[rt][ct][r] + sQW[eh][col] + bf2f(sH[hidx]) + dv*w320[ct];
          float h = x / (1.0f + __expf(-x));
          sH[hidx] = f2bf(h);
        }
      }
    }
  }
  __syncthreads();            // all GEMM1 sA reads done; sA alias region now usable

  #pragma unroll
  for (int rt = 0; rt < 4; ++rt)
    #pragma unroll
    for (int ct = 0; ct < 2; ++ct) acc[rt][ct] = (f32x4){0.f,0.f,0.f,0.f};

  // ---- GEMM2: h @ W2 ----
  #pragma unroll
  for (int ks = 0; ks < 4; ++ks) {
    bf16x8 af[4], bfr[2];
    #pragma unroll
    for (int rt = 0; rt < 4; ++rt) {
      int row = rh*64 + rt*16 + l15;
      int aidx = (row*128 + ks*32 + l4*8) ^ ((row & 7) << 3);
      af[rt] = *(const bf16x8*)(&sH[aidx]);
    }
    #pragma unroll
    for (int ct = 0; ct < 2; ++ct) {
      int col = c4*32 + ct*16 + l15;
      bfr[ct] = *(const bf16x8*)(&Wt2[col*128 + ks*32 + l4*8]);
    }
    #pragma unroll
    for (int rt = 0; rt < 4; ++rt)
      #pragma unroll
      for (int ct = 0; ct < 2; ++ct)
        acc[rt][ct] = __builtin_amdgcn_mfma_f32_16x16x32_bf16(af[rt], bfr[ct], acc[rt][ct], 0, 0, 0);
  }

  // ---- epilogue 2: silu, dot W3, reduce over this wave's 32 cols -> spart ----
  {
    float b2r[2], w3r[2];
    #pragma unroll
    for (int ct = 0; ct < 2; ++ct) {
      int col = c4*32 + ct*16 + l15;
      b2r[ct] = b2[col]; w3r[ct] = W3[col];
    }
    #pragma unroll
    for (int rt = 0; rt < 4; ++rt) {
      #pragma unroll
      for (int r = 0; r < 4; ++r) {
        float part = 0.f;
        #pragma unroll
        for (int ct = 0; ct < 2; ++ct) {
          float x = acc[rt][ct][r] + b2r[ct];
          float h = x / (1.0f + __expf(-x));
          part = fmaf(h, w3r[ct], part);
        }
        part += __shfl_xor(part, 1, 64);
        part += __shfl_xor(part, 2, 64);
        part += __shfl_xor(part, 4, 64);
        part += __shfl_xor(part, 8, 64);
        if (l15 == 0) spart[c4*128 + rh*64 + rt*16 + l4*4 + r] = part;
      }
    }
  }
  __syncthreads();

  // ---- softmax + coord update: wave w (<4) -> edge w ----
  if (w < 4 && l < 32) {
    const int eh = w;
    const int row = eh*32 + l;
    float raw = spart[row] + spart[128 + row] + spart[256 + row] + spart[384 + row] + b3[0];
    float sc = (sDist[row] <= CUTF) ? raw : 0.0f;
    float m = sc;
    #pragma unroll
    for (int mm = 1; mm < 32; mm <<= 1) m = fmaxf(m, __shfl_xor(m, mm, 64));
    m = fmaxf(m, 0.0f);
    float ex = __expf(sc - m);
    float Z = ex;
    #pragma unroll
    for (int mm = 1; mm < 32; mm <<= 1) Z += __shfl_xor(Z, mm, 64);
    Z += 8160.0f * __expf(-m);               // (E-K) zero-score tail
    float wv = ex / Z;
    swk[eh*32 + l] = wv;
    int j = sIdx[row];
    float g = wv * gates[j];
    float4 cee = cen4[eBase + eh], cjj = cen4[j];
    float cx = g*(cee.x - cjj.x), cy = g*(cee.y - cjj.y), cz = g*(cee.z - cjj.z);
    #pragma unroll
    for (int mm = 1; mm < 32; mm <<= 1) {
      cx += __shfl_xor(cx, mm, 64);
      cy += __shfl_xor(cy, mm, 64);
      cz += __shfl_xor(cz, mm, 64);
    }
    if (l == 0) {
      int e = eBase + eh;
      outc[e*3+0] = ec[e*3+0] + cx;
      outc[e*3+1] = ec[e*3+1] + cy;
      outc[e*3+2] = ec[e*3+2] + cz;
    }
  }
  __syncthreads();

  // ---- weighted V (prefetched regs) + residual -> sUB (bf16 upd tile) ----
  {
    const int eh = t >> 7, col = t & 127;
    float acc2 = 0.f;
    #pragma unroll
    for (int kk = 0; kk < 16; ++kk) {
      acc2 = fmaf(swk[eh*32 + 2*kk],     bf2f((u16)(vp[kk] & 0xffffu)), acc2);
      acc2 = fmaf(swk[eh*32 + 2*kk + 1], bf2f((u16)(vp[kk] >> 16)),     acc2);
    }
    sUB[eh*128 + col] = f2bf(ef[(size_t)(eBase + eh)*HID + col] + acc2);
  }
  __syncthreads();

  // ---- Wo projection via MFMA: D[edge][col] = upd(bf16) @ Wo ----
  // A rows = edges 0-3 (rows 4-15 stale garbage: row-independent, ignored).
  {
    f32x4 aw = (f32x4){0.f,0.f,0.f,0.f};
    #pragma unroll
    for (int ks = 0; ks < 4; ++ks) {
      bf16x8 afu = *(const bf16x8*)(&sUB[l15*128 + ks*32 + l4*8]);
      bf16x8 bfo = *(const bf16x8*)(&Wot[(size_t)(w*16 + l15)*128 + ks*32 + l4*8]);
      aw = __builtin_amdgcn_mfma_f32_16x16x32_bf16(afu, bfo, aw, 0, 0, 0);
    }
    if (l4 == 0) {                 // rows 0-3 = edges
      #pragma unroll
      for (int r = 0; r < 4; ++r)
        sWo[r*128 + w*16 + l15] = aw[r];
    }
  }
  __syncthreads();

  // ---- residual + LayerNorm ----
  {
    const int eh = t >> 7, o = t & 127;
    const int e = eBase + eh;
    float x = ef[(size_t)e*HID + o] + sWo[eh*128 + o] + bo[o];
    float s1 = x, s2 = x*x;
    #pragma unroll
    for (int m = 1; m < 64; m <<= 1) {
      s1 += __shfl_xor(s1, m, 64);
      s2 += __shfl_xor(s2, m, 64);
    }
    if (l == 0) { sred[w*2+0] = s1; sred[w*2+1] = s2; }
    __syncthreads();
    float t1 = sred[(eh*2)*2+0] + sred[(eh*2+1)*2+0];
    float t2 = sred[(eh*2)*2+1] + sred[(eh*2+1)*2+1];
    float mu = t1 * (1.0f/128.0f);
    float var = t2 * (1.0f/128.0f) - mu*mu;
    float rs = rsqrtf(var + LNEPS);
    outf[(size_t)e*HID + o] = (x - mu)*rs*gamma[o] + beta[o];
  }
}

extern "C" void kernel_launch(void* const* d_in, const int* in_sizes, int n_in,
                              void* d_out, int out_size, void* d_ws, size_t ws_size,
                              hipStream_t stream) {
  const float* ef   = (const float*)d_in[0];
  const float* ec   = (const float*)d_in[1];
  const float* nc   = (const float*)d_in[2];
  const float* Wq   = (const float*)d_in[3];
  const float* Wk   = (const float*)d_in[4];
  const float* Wv   = (const float*)d_in[5];
  const float* W1   = (const float*)d_in[6];
  const float* b1   = (const float*)d_in[7];
  const float* W2   = (const float*)d_in[8];
  const float* b2   = (const float*)d_in[9];
  const float* W3   = (const float*)d_in[10];
  const float* b3   = (const float*)d_in[11];
  const float* Wg1  = (const float*)d_in[12];
  const float* bg1  = (const float*)d_in[13];
  const float* Wg2  = (const float*)d_in[14];
  const float* bg2  = (const float*)d_in[15];
  const float* Wo   = (const float*)d_in[16];
  const float* bo   = (const float*)d_in[17];
  const float* gamma= (const float*)d_in[18];
  const float* beta = (const float*)d_in[19];
  const float* centers = (const float*)d_in[20];
  const float* widths  = (const float*)d_in[21];
  const int*   eidx    = (const int*)d_in[22];

  float* outf = (float*)d_out;
  float* outc = outf + (size_t)E_N * HID;

  // workspace layout (16B-aligned chunks first)
  float4* cen4 = (float4*)d_ws;                        // 8192 * 16B
  u16*   kjp   = (u16*)(cen4 + E_N);                   // E * 256 bf16 (4 MB)
  u16*   vfb   = kjp + (size_t)E_N*256;                // E * 128 bf16 (2 MB)
  u16*   Wt1r  = vfb + (size_t)E_N*128;                // 128*64 bf16
  u16*   Wt2   = Wt1r + 128*64;                        // 128*128 bf16
  u16*   Wqt   = Wt2  + 128*128;
  u16*   Wkt   = Wqt  + 128*128;
  u16*   Wvt   = Wkt  + 128*128;
  u16*   Wqct  = Wvt  + 128*128;
  u16*   Wkct  = Wqct + 128*128;
  u16*   Wvgt  = Wkct + 128*128;
  u16*   Wot   = Wvgt + 128*128;
  int*   idx   = (int*)(Wot + 128*128);
  float* qf    = (float*)(idx + E_N*KNB);
  float* qW1   = qf + (size_t)E_N*HID;
  float* gates = qW1 + (size_t)E_N*HID;

  k_pre<<<672, 256, 0, stream>>>(W1, W2, Wq, Wk, Wv, Wg1, Wo, nc, eidx,
                                 Wt1r, Wt2, Wqt, Wkt, Wvt, Wqct, Wkct, Wvgt, Wot, cen4);
  k_topk<<<E_N/8, 256, 0, stream>>>(cen4, idx);
  k_qkv<<<E_N/32, 256, 0, stream>>>(ef, Wqt, Wkt, Wvt, Wqct, Wkct, Wvgt,
                                    b1, bg1, Wg2, bg2, qf, qW1, kjp, vfb, gates);
  k_mega<<<E_N*KNB/128, 512, 0, stream>>>(idx, qf, cen4, qW1, kjp, vfb, gates, Wt1r, Wt2,
                                          Wot, W1, b2, W3, b3, centers, widths, ef, ec,
                                          bo, gamma, beta, outf, outc);
}

// Round 19
// 186.253 us; speedup vs baseline: 1.1281x; 1.0053x over previous
//
#include <hip/hip_runtime.h>
#include <math.h>

#define E_N   8192
#define HID   128
#define NRAD  64
#define KNB   32
#define CUTF  10.0f
#define LNEPS 1e-5f

typedef unsigned short u16;
typedef unsigned int   u32;
typedef unsigned long long u64;
typedef __bf16 bf16x8 __attribute__((ext_vector_type(8)));
typedef u16    u16x8  __attribute__((ext_vector_type(8)));
typedef float  f32x4  __attribute__((ext_vector_type(4)));

__device__ __forceinline__ u16 f2bf(float f) {          // native HW cvt (RNE)
  __bf16 h = (__bf16)f;
  return __builtin_bit_cast(u16, h);
}
__device__ __forceinline__ float bf2f(u16 v) {
  return __uint_as_float(((u32)v) << 16);
}

__device__ __forceinline__ u64 shflx64(u64 v, int m) {
  int lo = __shfl_xor((int)(v & 0xffffffffull), m, 64);
  int hi = __shfl_xor((int)(v >> 32), m, 64);
  return ((u64)(unsigned)hi << 32) | (unsigned)lo;
}

// monotone-u32 key of squared distance; fmaf-pinned so pass1/pass2 agree bitwise
__device__ __forceinline__ u32 d2key(const float4 me, const float4 c) {
  float dot = fmaf(me.x, c.x, fmaf(me.y, c.y, me.z * c.z));
  float d2  = fmaf(-2.0f, dot, me.w + c.w);     // gram trick, as in reference
  u32 u = __float_as_uint(d2);
  return u ^ (((u32)((int)u >> 31)) | 0x80000000u);
}

// ---------------- kernel 0: merged prep (bf16 panels / fused products / centers) ----------------
__global__ __launch_bounds__(256) void k_pre(
    const float* __restrict__ W1, const float* __restrict__ W2,
    const float* __restrict__ Wq, const float* __restrict__ Wk,
    const float* __restrict__ Wv, const float* __restrict__ Wg1,
    const float* __restrict__ Wo,
    const float* __restrict__ nc, const int* __restrict__ ei,
    u16* __restrict__ Wt1r, u16* __restrict__ Wt2,
    u16* __restrict__ Wqt, u16* __restrict__ Wkt, u16* __restrict__ Wvt,
    u16* __restrict__ Wqct, u16* __restrict__ Wkct, u16* __restrict__ Wvgt,
    u16* __restrict__ Wot,
    float4* __restrict__ cen4) {
  const int b = blockIdx.x, t = threadIdx.x;
  if (b < 128) {
    if (t < 64)       Wt1r[b*64 + t]      = f2bf(W1[(256+t)*HID + b]);   // rbf rows 256..319
    else if (t < 192) Wt2[b*HID + (t-64)] = f2bf(W2[(t-64)*HID + b]);
  } else if (b < 256) {
    const int r = b - 128, o = t & 127;
    float a = 0.f;
    if (t < 128) {
      #pragma unroll 8
      for (int m = 0; m < 128; ++m) a = fmaf(Wq[r*128+m], W1[m*128+o], a);
      Wqct[o*128 + r] = f2bf(a);
    } else {
      #pragma unroll 8
      for (int m = 0; m < 128; ++m) a = fmaf(Wk[r*128+m], W1[(128+m)*128+o], a);
      Wkct[o*128 + r] = f2bf(a);
    }
  } else if (b < 384) {
    const int r = b - 256;
    if (t < 128) {
      float a = 0.f;
      #pragma unroll 8
      for (int m = 0; m < 128; ++m) a = fmaf(Wv[r*128+m], Wg1[m*128+t], a);
      Wvgt[t*128 + r] = f2bf(a);
    }
  } else if (b < 512) {
    const int c = b - 384;
    if (t < 128) Wqt[c*128 + t]       = f2bf(Wq[t*128 + c]);
    else         Wkt[c*128 + (t-128)] = f2bf(Wk[(t-128)*128 + c]);
  } else if (b < 640) {
    const int c = b - 512;
    if (t < 128) Wvt[c*128 + t]       = f2bf(Wv[t*128 + c]);
    else         Wot[c*128 + (t-128)] = f2bf(Wo[(t-128)*128 + c]);
  } else {
    const int e = (b - 640)*256 + t;
    if (e < E_N) {
      int a = ei[e], bb = ei[E_N + e];
      float x = (nc[a*3+0] + nc[bb*3+0]) * 0.5f;
      float y = (nc[a*3+1] + nc[bb*3+1]) * 0.5f;
      float z = (nc[a*3+2] + nc[bb*3+2]) * 0.5f;
      cen4[e] = make_float4(x, y, z, x*x + y*y + z*z);
    }
  }
}

// ---------------- kernel 2: top-K, 8 rows/block, two-pass prune + exact lex rank ----------------
__global__ __launch_bounds__(256) void k_topk(const float4* __restrict__ cen4,
                                              int* __restrict__ idxo) {
  const int row0 = blockIdx.x * 8;
  const int t = threadIdx.x;
  const int lane = t & 63, w = t >> 6;
  __shared__ __align__(16) u32 smin[8][256];   // 8 KiB
  __shared__ __align__(16) u64 comp[2048];     // 16 KiB survivor buffer
  __shared__ u32 sU[8];
  __shared__ u32 scnt, scnt_r[8];
  __shared__ u64 wred[4];
  __shared__ u64 winner;

  if (t == 0) scnt = 0;
  if (t < 8) scnt_r[t] = 0;

  float4 me[8];
  #pragma unroll
  for (int r = 0; r < 8; ++r) me[r] = cen4[row0 + r];

  // ---- pass 1: running mins for 8 rows ----
  u32 mn[8];
  #pragma unroll
  for (int r = 0; r < 8; ++r) mn[r] = 0xFFFFFFFFu;
  for (int s = 0; s < 32; ++s) {
    float4 c = cen4[t + (s << 8)];
    #pragma unroll
    for (int r = 0; r < 8; ++r) {
      u32 k = d2key(me[r], c);
      mn[r] = k < mn[r] ? k : mn[r];
    }
  }
  #pragma unroll
  for (int r = 0; r < 8; ++r) smin[r][t] = mn[r];
  __syncthreads();

  // ---- per-row bound: wave w handles rows 2w, 2w+1; in-wave radix bisect ----
  #pragma unroll
  for (int rr = 0; rr < 2; ++rr) {
    const int r = w*2 + rr;
    uint4 vv = *(const uint4*)&smin[r][lane*4];
    u32 P = 0;
    u32 rem = 31;
    #pragma unroll 1
    for (int b = 31; b >= 12; --b) {
      u32 bit = 1u << b;
      bool pm0 = ((u64)(vv.x ^ P) >> (b+1)) == 0ull;
      bool pm1 = ((u64)(vv.y ^ P) >> (b+1)) == 0ull;
      bool pm2 = ((u64)(vv.z ^ P) >> (b+1)) == 0ull;
      bool pm3 = ((u64)(vv.w ^ P) >> (b+1)) == 0ull;
      u32 c0 = (u32)__popcll(__ballot(pm0 && !(vv.x & bit)))
             + (u32)__popcll(__ballot(pm1 && !(vv.y & bit)))
             + (u32)__popcll(__ballot(pm2 && !(vv.z & bit)))
             + (u32)__popcll(__ballot(pm3 && !(vv.w & bit)));
      if (rem >= c0) { P |= bit; rem -= c0; }
    }
    if (lane == 0) sU[r] = P | 0xFFFu;
  }
  __syncthreads();

  // ---- pass 2: recompute keys, compact survivors ----
  u32 Ur[8];
  #pragma unroll
  for (int r = 0; r < 8; ++r) Ur[r] = sU[r];
  for (int s = 0; s < 32; ++s) {
    float4 c = cen4[t + (s << 8)];
    #pragma unroll
    for (int r = 0; r < 8; ++r) {
      u32 k = d2key(me[r], c);
      if (k <= Ur[r]) {
        u32 pos = atomicAdd(&scnt, 1u);
        atomicAdd(&scnt_r[r], 1u);
        if (pos < 2048u)
          comp[pos] = ((u64)r << 45) | (((u64)k) << 13) | (u32)(t + (s << 8));
      }
    }
  }
  __syncthreads();
  const int cnt = (int)scnt;

  if (cnt <= 2048) {
    u32 off[8];
    off[0] = 0;
    #pragma unroll
    for (int r = 1; r < 8; ++r) off[r] = off[r-1] + scnt_r[r-1];
    for (int i = t; i < cnt; i += 256) {
      u64 mev = comp[i];
      int rk = 0;
      int j2 = 0;
      for (; j2 + 2 <= cnt; j2 += 2) {
        ulonglong2 pr = *(const ulonglong2*)&comp[j2];
        rk += (pr.x < mev) ? 1 : 0;
        rk += (pr.y < mev) ? 1 : 0;
      }
      if (j2 < cnt) rk += (comp[j2] < mev) ? 1 : 0;
      int r = (int)(mev >> 45);
      int rank = rk - (int)off[r];
      if (rank < KNB) idxo[(row0 + r)*KNB + rank] = (int)(mev & 0x1FFFull);
    }
  } else {
    // overflow fallback (never taken statistically): exact per-row extract-min
    for (int r = 0; r < 8; ++r) {
      float4 mer = cen4[row0 + r];
      u32 taken = 0;
      for (int kk2 = 0; kk2 < KNB; ++kk2) {
        u64 lk = 0xFFFFFFFFFFFFFFFFull;
        for (int s = 0; s < 32; ++s) {
          if (taken & (1u << s)) continue;
          float4 c = cen4[t + (s << 8)];
          u64 kx = (((u64)d2key(mer, c)) << 13) | (u32)(t + (s << 8));
          lk = kx < lk ? kx : lk;
        }
        #pragma unroll
        for (int m = 1; m < 64; m <<= 1) {
          u64 o = shflx64(lk, m);
          lk = o < lk ? o : lk;
        }
        if (lane == 0) wred[w] = lk;
        __syncthreads();
        if (t == 0) {
          u64 w0 = wred[0] < wred[1] ? wred[0] : wred[1];
          u64 w1 = wred[2] < wred[3] ? wred[2] : wred[3];
          winner = w0 < w1 ? w0 : w1;
          idxo[(row0 + r)*KNB + kk2] = (int)(winner & 0x1FFFull);
        }
        __syncthreads();
        u64 jw = winner & 0x1FFFull;
        if (((u32)jw & 255u) == (u32)t) taken |= 1u << ((u32)jw >> 8);
        __syncthreads();
      }
    }
  }
}

// ---------------- kernel 3: 6-panel MFMA projections, 32 edges/block ----------------
__global__ __launch_bounds__(256) void k_qkv(const float* __restrict__ ef,
    const u16* __restrict__ Wqt, const u16* __restrict__ Wkt, const u16* __restrict__ Wvt,
    const u16* __restrict__ Wqct, const u16* __restrict__ Wkct, const u16* __restrict__ Wvgt,
    const float* __restrict__ b1, const float* __restrict__ bg1,
    const float* __restrict__ Wg2, const float* __restrict__ bg2,
    float* __restrict__ qf, float* __restrict__ qW1,
    u16* __restrict__ kjp, u16* __restrict__ vfb, float* __restrict__ gates) {
  __shared__ u16 sE[32*128];      // ef tile bf16, swizzled (8 KiB)
  __shared__ float spart[4][32];
  const int t = threadIdx.x;
  const int w = t >> 6, l = t & 63;
  const int l15 = l & 15, l4 = l >> 4;
  const int e0 = blockIdx.x * 32;
  const int colw = w * 32;

  // stage ef tile
  {
    const int srow = t >> 3, sb = t & 7;
    const float4* src = (const float4*)(ef + (size_t)(e0 + srow)*HID + sb*16);
    #pragma unroll
    for (int g = 0; g < 2; ++g) {
      float4 v0 = src[g*2], v1 = src[g*2+1];
      u16x8 vv;
      vv[0]=f2bf(v0.x); vv[1]=f2bf(v0.y); vv[2]=f2bf(v0.z); vv[3]=f2bf(v0.w);
      vv[4]=f2bf(v1.x); vv[5]=f2bf(v1.y); vv[6]=f2bf(v1.z); vv[7]=f2bf(v1.w);
      int widx = (srow*128 + sb*16 + g*8) ^ ((srow & 7) << 3);
      *(u16x8*)(&sE[widx]) = vv;
    }
  }
  __syncthreads();

  // preload all A fragments (2 row-tiles x 4 k-slices)
  bf16x8 afq[2][4];
  #pragma unroll
  for (int rt = 0; rt < 2; ++rt) {
    int row = rt*16 + l15;
    #pragma unroll
    for (int ks = 0; ks < 4; ++ks) {
      int aidx = (row*128 + ks*32 + l4*8) ^ ((row & 7) << 3);
      afq[rt][ks] = *(const bf16x8*)(&sE[aidx]);
    }
  }

  f32x4 a2[2][2];
  auto gemm_panel = [&](const u16* __restrict__ P) {
    #pragma unroll
    for (int rt = 0; rt < 2; ++rt)
      #pragma unroll
      for (int ct = 0; ct < 2; ++ct) a2[rt][ct] = (f32x4){0.f,0.f,0.f,0.f};
    #pragma unroll
    for (int ks = 0; ks < 4; ++ks) {
      bf16x8 bfr[2];
      #pragma unroll
      for (int ct = 0; ct < 2; ++ct)
        bfr[ct] = *(const bf16x8*)(&P[(colw + ct*16 + l15)*128 + ks*32 + l4*8]);
      #pragma unroll
      for (int rt = 0; rt < 2; ++rt)
        #pragma unroll
        for (int ct = 0; ct < 2; ++ct)
          a2[rt][ct] = __builtin_amdgcn_mfma_f32_16x16x32_bf16(afq[rt][ks], bfr[ct], a2[rt][ct], 0, 0, 0);
    }
  };

  // q
  gemm_panel(Wqt);
  #pragma unroll
  for (int rt = 0; rt < 2; ++rt)
    #pragma unroll
    for (int r = 0; r < 4; ++r) {
      size_t e = e0 + rt*16 + l4*4 + r;
      #pragma unroll
      for (int ct = 0; ct < 2; ++ct)
        qf[e*HID + colw + ct*16 + l15] = a2[rt][ct][r];
    }
  // k
  gemm_panel(Wkt);
  #pragma unroll
  for (int rt = 0; rt < 2; ++rt)
    #pragma unroll
    for (int r = 0; r < 4; ++r) {
      size_t e = e0 + rt*16 + l4*4 + r;
      #pragma unroll
      for (int ct = 0; ct < 2; ++ct)
        kjp[e*256 + 128 + colw + ct*16 + l15] = f2bf(a2[rt][ct][r]);
    }
  // v
  gemm_panel(Wvt);
  #pragma unroll
  for (int rt = 0; rt < 2; ++rt)
    #pragma unroll
    for (int r = 0; r < 4; ++r) {
      size_t e = e0 + rt*16 + l4*4 + r;
      #pragma unroll
      for (int ct = 0; ct < 2; ++ct)
        vfb[e*HID + colw + ct*16 + l15] = f2bf(a2[rt][ct][r]);
    }
  // qW1 = ef@(Wq@W1q) + b1
  gemm_panel(Wqct);
  {
    float b1r[2];
    #pragma unroll
    for (int ct = 0; ct < 2; ++ct) b1r[ct] = b1[colw + ct*16 + l15];
    #pragma unroll
    for (int rt = 0; rt < 2; ++rt)
      #pragma unroll
      for (int r = 0; r < 4; ++r) {
        size_t e = e0 + rt*16 + l4*4 + r;
        #pragma unroll
        for (int ct = 0; ct < 2; ++ct)
          qW1[e*HID + colw + ct*16 + l15] = a2[rt][ct][r] + b1r[ct];
      }
  }
  // kW1 = ef@(Wk@W1k)
  gemm_panel(Wkct);
  #pragma unroll
  for (int rt = 0; rt < 2; ++rt)
    #pragma unroll
    for (int r = 0; r < 4; ++r) {
      size_t e = e0 + rt*16 + l4*4 + r;
      #pragma unroll
      for (int ct = 0; ct < 2; ++ct)
        kjp[e*256 + colw + ct*16 + l15] = f2bf(a2[rt][ct][r]);
    }
  // gates: g1 = silu(ef@(Wv@Wg1) + bg1); gate = sigmoid(g1.Wg2 + bg2)
  gemm_panel(Wvgt);
  {
    float bgr[2], w3r[2];
    #pragma unroll
    for (int ct = 0; ct < 2; ++ct) {
      int col = colw + ct*16 + l15;
      bgr[ct] = bg1[col]; w3r[ct] = Wg2[col];
    }
    #pragma unroll
    for (int rt = 0; rt < 2; ++rt)
      #pragma unroll
      for (int r = 0; r < 4; ++r) {
        float part = 0.f;
        #pragma unroll
        for (int ct = 0; ct < 2; ++ct) {
          float x = a2[rt][ct][r] + bgr[ct];
          float g = x / (1.0f + __expf(-x));
          part = fmaf(g, w3r[ct], part);
        }
        part += __shfl_xor(part, 1, 64);
        part += __shfl_xor(part, 2, 64);
        part += __shfl_xor(part, 4, 64);
        part += __shfl_xor(part, 8, 64);
        if (l15 == 0) spart[w][rt*16 + l4*4 + r] = part;
      }
  }
  __syncthreads();
  if (t < 32)
    gates[e0 + t] = 1.0f / (1.0f + __expf(-(spart[0][t] + spart[1][t] + spart[2][t] + spart[3][t] + bg2[0])));
}

// ---------------- kernel 5: mega (MLP + softmax + combine + Wo-MFMA + LayerNorm), 4 edges/block ----------------
__global__ __launch_bounds__(512) void k_mega(
    const int* __restrict__ idx,
    const float* __restrict__ qf,
    const float4* __restrict__ cen4,
    const float* __restrict__ qW1, const u16* __restrict__ kjp,
    const u16* __restrict__ vfb, const float* __restrict__ gates,
    const u16* __restrict__ Wt1r, const u16* __restrict__ Wt2,
    const u16* __restrict__ Wot,
    const float* __restrict__ W1,
    const float* __restrict__ b2, const float* __restrict__ W3,
    const float* __restrict__ b3,
    const float* __restrict__ centers, const float* __restrict__ widths,
    const float* __restrict__ ef, const float* __restrict__ ec,
    const float* __restrict__ bo,
    const float* __restrict__ gamma, const float* __restrict__ beta,
    float* __restrict__ outf, float* __restrict__ outc) {
  __shared__ u16 sH[128*128];     // 32 KiB: kW1[j] tile -> in-place h tile
  __shared__ u16 sA[128*64];      // 16 KiB: rbf tile; aliased after GEMM1 drain:
  float* spart = (float*)sA;            // [4][128] col-slab partial scores (f32 0..511)
  float* swk   = (float*)sA + 512;      // [4][32]  softmax weights        (512..639)
  float* sred  = (float*)sA + 640;      // [8][2]   LN partial sums        (640..655)
  float* sWo   = (float*)sA + 656;      // [4][128] Wo-MFMA output         (656..1167)
  u16*   sUB   = (u16*)((float*)sA + 1168); // [16][136] bf16 upd tile, +8 u16 row pad
                                            // (row stride 272B = 68 dw -> banks spread;
                                            //  rows 4-15 garbage, row-independent MFMA)
  __shared__ float sQW[4][128];   // 2 KiB
  __shared__ float sDot[128];
  __shared__ float sDist[128];
  __shared__ int   sIdx[128];

  const int t  = threadIdx.x;
  const int w  = t >> 6, l = t & 63;
  const int l15 = l & 15, l4 = l >> 4;
  const int c4 = w & 3, rh = w >> 2;
  const int rowbase = blockIdx.x * 128;
  const int eBase = rowbase >> 5;           // four edges per block

  // ---- stage: kW1[j] tile (vectorized gather -> sH), dot, dist, rbf -> sA ----
  const int srow = t >> 2, sb = t & 3;      // 128 rows x 4 threads
  const int sp = rowbase + srow;
  const int se = sp >> 5;
  const int sj = idx[sp];
  {
    const u16x8* kw = (const u16x8*)(kjp + (size_t)sj*256 + sb*32);
    #pragma unroll
    for (int g = 0; g < 4; ++g) {
      int widx = (srow*128 + sb*32 + g*8) ^ ((srow & 7) << 3);
      *(u16x8*)(&sH[widx]) = kw[g];
    }
  }
  // q.k dot: q f32 x k bf16 (packed row), 4 lanes/row
  const u16x8* kb = (const u16x8*)(kjp + (size_t)sj*256 + 128 + sb*32);
  const float4* q4 = (const float4*)(qf + (size_t)se*HID) + sb*8;
  float dt = 0.f;
  #pragma unroll
  for (int i = 0; i < 4; ++i) {
    u16x8 kv8 = kb[i];
    float4 qa = q4[i*2], qb = q4[i*2+1];
    dt += bf2f(kv8[0])*qa.x + bf2f(kv8[1])*qa.y + bf2f(kv8[2])*qa.z + bf2f(kv8[3])*qa.w
        + bf2f(kv8[4])*qb.x + bf2f(kv8[5])*qb.y + bf2f(kv8[6])*qb.z + bf2f(kv8[7])*qb.w;
  }
  dt += __shfl_xor(dt, 1, 64);
  dt += __shfl_xor(dt, 2, 64);
  // geometry
  float4 ce = cen4[se], cj = cen4[sj];
  float ddx = ce.x - cj.x, ddy = ce.y - cj.y, ddz = ce.z - cj.z;
  const float sdist = sqrtf(ddx*ddx + ddy*ddy + ddz*ddz);
  const float sincut = (sdist <= CUTF) ? 1.0f : 0.0f;
  if (sb == 0) { sDot[srow] = dt; sDist[srow] = sdist; }
  {
    u16 tmp[16];
    #pragma unroll
    for (int i4 = 0; i4 < 4; ++i4) {
      float4 cc = *(const float4*)(centers + sb*16 + i4*4);
      float4 ww = *(const float4*)(widths  + sb*16 + i4*4);
      float c4v[4] = {cc.x,cc.y,cc.z,cc.w}, w4[4] = {ww.x,ww.y,ww.z,ww.w};
      #pragma unroll
      for (int jj = 0; jj < 4; ++jj) {
        float df = sdist - c4v[jj];
        tmp[i4*4+jj] = f2bf(__expf(-w4[jj]*df*df) * sincut);
      }
    }
    #pragma unroll
    for (int g = 0; g < 2; ++g) {
      u16x8 vv;
      #pragma unroll
      for (int jj = 0; jj < 8; ++jj) vv[jj] = tmp[g*8+jj];
      int widx = (srow*64 + sb*16 + g*8) ^ ((srow & 7) << 3);
      *(u16x8*)(&sA[widx]) = vv;
    }
  }
  sQW[t >> 7][t & 127] = qW1[(size_t)(eBase + (t >> 7))*HID + (t & 127)];
  if (t < 128) sIdx[t] = idx[rowbase + t];

  // ---- LAST loads of the phase: vfb prefetch for the combine tail ----
  u32 vp[16];
  {
    const int eh2 = t >> 7, colp = t & 127;
    const int ib = rowbase + eh2*32;
    #pragma unroll
    for (int kk = 0; kk < 16; ++kk) {
      int j0 = idx[ib + 2*kk], j1 = idx[ib + 2*kk + 1];
      u32 a = vfb[(size_t)j0*HID + colp];
      u32 b = vfb[(size_t)j1*HID + colp];
      vp[kk] = a | (b << 16);
    }
  }
  __syncthreads();

  f32x4 acc[4][2];
  #pragma unroll
  for (int rt = 0; rt < 4; ++rt)
    #pragma unroll
    for (int ct = 0; ct < 2; ++ct) acc[rt][ct] = (f32x4){0.f,0.f,0.f,0.f};

  // ---- GEMM1: rbf (K=64) ----
  #pragma unroll
  for (int ks = 0; ks < 2; ++ks) {
    bf16x8 af[4], bfr[2];
    #pragma unroll
    for (int rt = 0; rt < 4; ++rt) {
      int row = rh*64 + rt*16 + l15;
      int aidx = (row*64 + ks*32 + l4*8) ^ ((row & 7) << 3);
      af[rt] = *(const bf16x8*)(&sA[aidx]);
    }
    #pragma unroll
    for (int ct = 0; ct < 2; ++ct) {
      int col = c4*32 + ct*16 + l15;
      bfr[ct] = *(const bf16x8*)(&Wt1r[col*64 + ks*32 + l4*8]);
    }
    #pragma unroll
    for (int rt = 0; rt < 4; ++rt)
      #pragma unroll
      for (int ct = 0; ct < 2; ++ct)
        acc[rt][ct] = __builtin_amdgcn_mfma_f32_16x16x32_bf16(af[rt], bfr[ct], acc[rt][ct], 0, 0, 0);
  }

  // ---- epilogue 1: x = acc + qW1[e] + kW1[j](sH in-place) + dot*w320; silu -> sH ----
  {
    float w320[2];
    #pragma unroll
    for (int ct = 0; ct < 2; ++ct) {
      int col = c4*32 + ct*16 + l15;
      w320[ct] = W1[320*HID + col];
    }
    #pragma unroll
    for (int rt = 0; rt < 4; ++rt) {
      #pragma unroll
      for (int r = 0; r < 4; ++r) {
        int row = rh*64 + rt*16 + l4*4 + r;
        float dv = sDot[row];
        int eh = row >> 5;
        #pragma unroll
        for (int ct = 0; ct < 2; ++ct) {
          int col = c4*32 + ct*16 + l15;
          int hidx = (row*128 + col) ^ ((row & 7) << 3);
          float x = acc[rt][ct][r] + sQW[eh][col] + bf2f(sH[hidx]) + dv*w320[ct];
          float h = x / (1.0f + __expf(-x));
          sH[hidx] = f2bf(h);
        }
      }
    }
  }
  __syncthreads();            // all GEMM1 sA reads done; sA alias region now usable

  #pragma unroll
  for (int rt = 0; rt < 4; ++rt)
    #pragma unroll
    for (int ct = 0; ct < 2; ++ct) acc[rt][ct] = (f32x4){0.f,0.f,0.f,0.f};

  // ---- GEMM2: h @ W2 ----
  #pragma unroll
  for (int ks = 0; ks < 4; ++ks) {
    bf16x8 af[4], bfr[2];
    #pragma unroll
    for (int rt = 0; rt < 4; ++rt) {
      int row = rh*64 + rt*16 + l15;
      int aidx = (row*128 + ks*32 + l4*8) ^ ((row & 7) << 3);
      af[rt] = *(const bf16x8*)(&sH[aidx]);
    }
    #pragma unroll
    for (int ct = 0; ct < 2; ++ct) {
      int col = c4*32 + ct*16 + l15;
      bfr[ct] = *(const bf16x8*)(&Wt2[col*128 + ks*32 + l4*8]);
    }
    #pragma unroll
    for (int rt = 0; rt < 4; ++rt)
      #pragma unroll
      for (int ct = 0; ct < 2; ++ct)
        acc[rt][ct] = __builtin_amdgcn_mfma_f32_16x16x32_bf16(af[rt], bfr[ct], acc[rt][ct], 0, 0, 0);
  }

  // ---- epilogue 2: silu, dot W3, reduce over this wave's 32 cols -> spart ----
  {
    float b2r[2], w3r[2];
    #pragma unroll
    for (int ct = 0; ct < 2; ++ct) {
      int col = c4*32 + ct*16 + l15;
      b2r[ct] = b2[col]; w3r[ct] = W3[col];
    }
    #pragma unroll
    for (int rt = 0; rt < 4; ++rt) {
      #pragma unroll
      for (int r = 0; r < 4; ++r) {
        float part = 0.f;
        #pragma unroll
        for (int ct = 0; ct < 2; ++ct) {
          float x = acc[rt][ct][r] + b2r[ct];
          float h = x / (1.0f + __expf(-x));
          part = fmaf(h, w3r[ct], part);
        }
        part += __shfl_xor(part, 1, 64);
        part += __shfl_xor(part, 2, 64);
        part += __shfl_xor(part, 4, 64);
        part += __shfl_xor(part, 8, 64);
        if (l15 == 0) spart[c4*128 + rh*64 + rt*16 + l4*4 + r] = part;
      }
    }
  }
  __syncthreads();

  // ---- softmax + coord update: wave w (<4) -> edge w ----
  if (w < 4 && l < 32) {
    const int eh = w;
    const int row = eh*32 + l;
    float raw = spart[row] + spart[128 + row] + spart[256 + row] + spart[384 + row] + b3[0];
    float sc = (sDist[row] <= CUTF) ? raw : 0.0f;
    float m = sc;
    #pragma unroll
    for (int mm = 1; mm < 32; mm <<= 1) m = fmaxf(m, __shfl_xor(m, mm, 64));
    m = fmaxf(m, 0.0f);
    float ex = __expf(sc - m);
    float Z = ex;
    #pragma unroll
    for (int mm = 1; mm < 32; mm <<= 1) Z += __shfl_xor(Z, mm, 64);
    Z += 8160.0f * __expf(-m);               // (E-K) zero-score tail
    float wv = ex / Z;
    swk[eh*32 + l] = wv;
    int j = sIdx[row];
    float g = wv * gates[j];
    float4 cee = cen4[eBase + eh], cjj = cen4[j];
    float cx = g*(cee.x - cjj.x), cy = g*(cee.y - cjj.y), cz = g*(cee.z - cjj.z);
    #pragma unroll
    for (int mm = 1; mm < 32; mm <<= 1) {
      cx += __shfl_xor(cx, mm, 64);
      cy += __shfl_xor(cy, mm, 64);
      cz += __shfl_xor(cz, mm, 64);
    }
    if (l == 0) {
      int e = eBase + eh;
      outc[e*3+0] = ec[e*3+0] + cx;
      outc[e*3+1] = ec[e*3+1] + cy;
      outc[e*3+2] = ec[e*3+2] + cz;
    }
  }
  __syncthreads();

  // ---- weighted V (prefetched regs) + residual -> sUB (bf16 upd tile, padded rows) ----
  {
    const int eh = t >> 7, col = t & 127;
    float acc2 = 0.f;
    #pragma unroll
    for (int kk = 0; kk < 16; ++kk) {
      acc2 = fmaf(swk[eh*32 + 2*kk],     bf2f((u16)(vp[kk] & 0xffffu)), acc2);
      acc2 = fmaf(swk[eh*32 + 2*kk + 1], bf2f((u16)(vp[kk] >> 16)),     acc2);
    }
    sUB[eh*136 + col] = f2bf(ef[(size_t)(eBase + eh)*HID + col] + acc2);
  }
  __syncthreads();

  // ---- Wo projection via MFMA: D[edge][col] = upd(bf16) @ Wo ----
  // A rows = edges 0-3 (rows 4-15 stale garbage: row-independent, ignored).
  // sUB row stride 136 u16 (272B = 68 dw): row l15 starts at bank 4*l15 mod 32
  // -> A-fragment reads spread over all 32 banks (was 16-way on bank 0).
  {
    f32x4 aw = (f32x4){0.f,0.f,0.f,0.f};
    #pragma unroll
    for (int ks = 0; ks < 4; ++ks) {
      bf16x8 afu = *(const bf16x8*)(&sUB[l15*136 + ks*32 + l4*8]);
      bf16x8 bfo = *(const bf16x8*)(&Wot[(size_t)(w*16 + l15)*128 + ks*32 + l4*8]);
      aw = __builtin_amdgcn_mfma_f32_16x16x32_bf16(afu, bfo, aw, 0, 0, 0);
    }
    if (l4 == 0) {                 // rows 0-3 = edges
      #pragma unroll
      for (int r = 0; r < 4; ++r)
        sWo[r*128 + w*16 + l15] = aw[r];
    }
  }
  __syncthreads();

  // ---- residual + LayerNorm ----
  {
    const int eh = t >> 7, o = t & 127;
    const int e = eBase + eh;
    float x = ef[(size_t)e*HID + o] + sWo[eh*128 + o] + bo[o];
    float s1 = x, s2 = x*x;
    #pragma unroll
    for (int m = 1; m < 64; m <<= 1) {
      s1 += __shfl_xor(s1, m, 64);
      s2 += __shfl_xor(s2, m, 64);
    }
    if (l == 0) { sred[w*2+0] = s1; sred[w*2+1] = s2; }
    __syncthreads();
    float t1 = sred[(eh*2)*2+0] + sred[(eh*2+1)*2+0];
    float t2 = sred[(eh*2)*2+1] + sred[(eh*2+1)*2+1];
    float mu = t1 * (1.0f/128.0f);
    float var = t2 * (1.0f/128.0f) - mu*mu;
    float rs = rsqrtf(var + LNEPS);
    outf[(size_t)e*HID + o] = (x - mu)*rs*gamma[o] + beta[o];
  }
}

extern "C" void kernel_launch(void* const* d_in, const int* in_sizes, int n_in,
                              void* d_out, int out_size, void* d_ws, size_t ws_size,
                              hipStream_t stream) {
  const float* ef   = (const float*)d_in[0];
  const float* ec   = (const float*)d_in[1];
  const float* nc   = (const float*)d_in[2];
  const float* Wq   = (const float*)d_in[3];
  const float* Wk   = (const float*)d_in[4];
  const float* Wv   = (const float*)d_in[5];
  const float* W1   = (const float*)d_in[6];
  const float* b1   = (const float*)d_in[7];
  const float* W2   = (const float*)d_in[8];
  const float* b2   = (const float*)d_in[9];
  const float* W3   = (const float*)d_in[10];
  const float* b3   = (const float*)d_in[11];
  const float* Wg1  = (const float*)d_in[12];
  const float* bg1  = (const float*)d_in[13];
  const float* Wg2  = (const float*)d_in[14];
  const float* bg2  = (const float*)d_in[15];
  const float* Wo   = (const float*)d_in[16];
  const float* bo   = (const float*)d_in[17];
  const float* gamma= (const float*)d_in[18];
  const float* beta = (const float*)d_in[19];
  const float* centers = (const float*)d_in[20];
  const float* widths  = (const float*)d_in[21];
  const int*   eidx    = (const int*)d_in[22];

  float* outf = (float*)d_out;
  float* outc = outf + (size_t)E_N * HID;

  // workspace layout (16B-aligned chunks first)
  float4* cen4 = (float4*)d_ws;                        // 8192 * 16B
  u16*   kjp   = (u16*)(cen4 + E_N);                   // E * 256 bf16 (4 MB)
  u16*   vfb   = kjp + (size_t)E_N*256;                // E * 128 bf16 (2 MB)
  u16*   Wt1r  = vfb + (size_t)E_N*128;                // 128*64 bf16
  u16*   Wt2   = Wt1r + 128*64;                        // 128*128 bf16
  u16*   Wqt   = Wt2  + 128*128;
  u16*   Wkt   = Wqt  + 128*128;
  u16*   Wvt   = Wkt  + 128*128;
  u16*   Wqct  = Wvt  + 128*128;
  u16*   Wkct  = Wqct + 128*128;
  u16*   Wvgt  = Wkct + 128*128;
  u16*   Wot   = Wvgt + 128*128;
  int*   idx   = (int*)(Wot + 128*128);
  float* qf    = (float*)(idx + E_N*KNB);
  float* qW1   = qf + (size_t)E_N*HID;
  float* gates = qW1 + (size_t)E_N*HID;

  k_pre<<<672, 256, 0, stream>>>(W1, W2, Wq, Wk, Wv, Wg1, Wo, nc, eidx,
                                 Wt1r, Wt2, Wqt, Wkt, Wvt, Wqct, Wkct, Wvgt, Wot, cen4);
  k_topk<<<E_N/8, 256, 0, stream>>>(cen4, idx);
  k_qkv<<<E_N/32, 256, 0, stream>>>(ef, Wqt, Wkt, Wvt, Wqct, Wkct, Wvgt,
                                    b1, bg1, Wg2, bg2, qf, qW1, kjp, vfb, gates);
  k_mega<<<E_N*KNB/128, 512, 0, stream>>>(idx, qf, cen4, qW1, kjp, vfb, gates, Wt1r, Wt2,
                                          Wot, W1, b2, W3, b3, centers, widths, ef, ec,
                                          bo, gamma, beta, outf, outc);
}

// Round 20
// 174.926 us; speedup vs baseline: 1.2011x; 1.0648x over previous
//
#include <hip/hip_runtime.h>
#include <math.h>

#define E_N   8192
#define HID   128
#define NRAD  64
#define KNB   32
#define CUTF  10.0f
#define LNEPS 1e-5f

typedef unsigned short u16;
typedef unsigned int   u32;
typedef unsigned long long u64;
typedef __bf16 bf16x8 __attribute__((ext_vector_type(8)));
typedef u16    u16x8  __attribute__((ext_vector_type(8)));
typedef float  f32x4  __attribute__((ext_vector_type(4)));

__device__ __forceinline__ u16 f2bf(float f) {          // native HW cvt (RNE)
  __bf16 h = (__bf16)f;
  return __builtin_bit_cast(u16, h);
}
__device__ __forceinline__ float bf2f(u16 v) {
  return __uint_as_float(((u32)v) << 16);
}

__device__ __forceinline__ u64 shflx64(u64 v, int m) {
  int lo = __shfl_xor((int)(v & 0xffffffffull), m, 64);
  int hi = __shfl_xor((int)(v >> 32), m, 64);
  return ((u64)(unsigned)hi << 32) | (unsigned)lo;
}

// monotone-u32 key of squared distance; fmaf-pinned so pass1/pass2 agree bitwise
__device__ __forceinline__ u32 d2key(const float4 me, const float4 c) {
  float dot = fmaf(me.x, c.x, fmaf(me.y, c.y, me.z * c.z));
  float d2  = fmaf(-2.0f, dot, me.w + c.w);     // gram trick, as in reference
  u32 u = __float_as_uint(d2);
  return u ^ (((u32)((int)u >> 31)) | 0x80000000u);
}

// ---------------- kernel 0: merged prep (bf16 panels / fused products / centers) ----------------
__global__ __launch_bounds__(256) void k_pre(
    const float* __restrict__ W1, const float* __restrict__ W2,
    const float* __restrict__ Wq, const float* __restrict__ Wk,
    const float* __restrict__ Wv, const float* __restrict__ Wg1,
    const float* __restrict__ Wo,
    const float* __restrict__ nc, const int* __restrict__ ei,
    u16* __restrict__ Wt1r, u16* __restrict__ Wt2,
    u16* __restrict__ Wqt, u16* __restrict__ Wkt, u16* __restrict__ Wvt,
    u16* __restrict__ Wqct, u16* __restrict__ Wkct, u16* __restrict__ Wvgt,
    u16* __restrict__ Wot,
    float4* __restrict__ cen4) {
  const int b = blockIdx.x, t = threadIdx.x;
  if (b < 128) {
    if (t < 64)       Wt1r[b*64 + t]      = f2bf(W1[(256+t)*HID + b]);   // rbf rows 256..319
    else if (t < 192) Wt2[b*HID + (t-64)] = f2bf(W2[(t-64)*HID + b]);
  } else if (b < 256) {
    const int r = b - 128, o = t & 127;
    float a = 0.f;
    if (t < 128) {
      #pragma unroll 8
      for (int m = 0; m < 128; ++m) a = fmaf(Wq[r*128+m], W1[m*128+o], a);
      Wqct[o*128 + r] = f2bf(a);
    } else {
      #pragma unroll 8
      for (int m = 0; m < 128; ++m) a = fmaf(Wk[r*128+m], W1[(128+m)*128+o], a);
      Wkct[o*128 + r] = f2bf(a);
    }
  } else if (b < 384) {
    const int r = b - 256;
    if (t < 128) {
      float a = 0.f;
      #pragma unroll 8
      for (int m = 0; m < 128; ++m) a = fmaf(Wv[r*128+m], Wg1[m*128+t], a);
      Wvgt[t*128 + r] = f2bf(a);
    }
  } else if (b < 512) {
    const int c = b - 384;
    if (t < 128) Wqt[c*128 + t]       = f2bf(Wq[t*128 + c]);
    else         Wkt[c*128 + (t-128)] = f2bf(Wk[(t-128)*128 + c]);
  } else if (b < 640) {
    const int c = b - 512;
    if (t < 128) Wvt[c*128 + t]       = f2bf(Wv[t*128 + c]);
    else         Wot[c*128 + (t-128)] = f2bf(Wo[(t-128)*128 + c]);
  } else {
    const int e = (b - 640)*256 + t;
    if (e < E_N) {
      int a = ei[e], bb = ei[E_N + e];
      float x = (nc[a*3+0] + nc[bb*3+0]) * 0.5f;
      float y = (nc[a*3+1] + nc[bb*3+1]) * 0.5f;
      float z = (nc[a*3+2] + nc[bb*3+2]) * 0.5f;
      cen4[e] = make_float4(x, y, z, x*x + y*y + z*z);
    }
  }
}

// ---------------- kernel 2+3 merged: top-K (blocks 0..1023) | qkv projections (1024..1279) ----------------
// Independent workloads (both depend only on k_pre); merged so qkv blocks
// backfill CUs while topk drains -> one dispatch boundary removed.
__global__ __launch_bounds__(256) void k_tq(
    const float4* __restrict__ cen4, int* __restrict__ idxo,
    const float* __restrict__ ef,
    const u16* __restrict__ Wqt, const u16* __restrict__ Wkt, const u16* __restrict__ Wvt,
    const u16* __restrict__ Wqct, const u16* __restrict__ Wkct, const u16* __restrict__ Wvgt,
    const float* __restrict__ b1, const float* __restrict__ bg1,
    const float* __restrict__ Wg2, const float* __restrict__ bg2,
    float* __restrict__ qf, float* __restrict__ qW1,
    u16* __restrict__ kjp, u16* __restrict__ vfb, float* __restrict__ gates) {
  __shared__ __align__(16) char pool[24704];
  const int t = threadIdx.x;
  const int lane = t & 63, w = t >> 6;

  if (blockIdx.x < E_N/8) {
    // ================= top-K path =================
    u64* comp   = (u64*)pool;                    // 2048 * 8
    u32* smin   = (u32*)(pool + 16384);          // 8*256 * 4
    u64* wred   = (u64*)(pool + 24576);          // 4 * 8
    u64* winner = (u64*)(pool + 24608);
    u32* sU     = (u32*)(pool + 24616);          // 8 * 4
    u32* scnt   = (u32*)(pool + 24648);
    u32* scnt_r = (u32*)(pool + 24652);          // 8 * 4

    const int row0 = blockIdx.x * 8;
    if (t == 0) *scnt = 0;
    if (t < 8) scnt_r[t] = 0;

    float4 me[8];
    #pragma unroll
    for (int r = 0; r < 8; ++r) me[r] = cen4[row0 + r];

    // pass 1: running mins for 8 rows
    u32 mn[8];
    #pragma unroll
    for (int r = 0; r < 8; ++r) mn[r] = 0xFFFFFFFFu;
    for (int s = 0; s < 32; ++s) {
      float4 c = cen4[t + (s << 8)];
      #pragma unroll
      for (int r = 0; r < 8; ++r) {
        u32 k = d2key(me[r], c);
        mn[r] = k < mn[r] ? k : mn[r];
      }
    }
    #pragma unroll
    for (int r = 0; r < 8; ++r) smin[r*256 + t] = mn[r];
    __syncthreads();

    // per-row bound: wave w handles rows 2w, 2w+1; in-wave radix bisect
    #pragma unroll
    for (int rr = 0; rr < 2; ++rr) {
      const int r = w*2 + rr;
      uint4 vv = *(const uint4*)&smin[r*256 + lane*4];
      u32 P = 0;
      u32 rem = 31;
      #pragma unroll 1
      for (int b = 31; b >= 12; --b) {
        u32 bit = 1u << b;
        bool pm0 = ((u64)(vv.x ^ P) >> (b+1)) == 0ull;
        bool pm1 = ((u64)(vv.y ^ P) >> (b+1)) == 0ull;
        bool pm2 = ((u64)(vv.z ^ P) >> (b+1)) == 0ull;
        bool pm3 = ((u64)(vv.w ^ P) >> (b+1)) == 0ull;
        u32 c0 = (u32)__popcll(__ballot(pm0 && !(vv.x & bit)))
               + (u32)__popcll(__ballot(pm1 && !(vv.y & bit)))
               + (u32)__popcll(__ballot(pm2 && !(vv.z & bit)))
               + (u32)__popcll(__ballot(pm3 && !(vv.w & bit)));
        if (rem >= c0) { P |= bit; rem -= c0; }
      }
      if (lane == 0) sU[r] = P | 0xFFFu;
    }
    __syncthreads();

    // pass 2: recompute keys, compact survivors
    u32 Ur[8];
    #pragma unroll
    for (int r = 0; r < 8; ++r) Ur[r] = sU[r];
    for (int s = 0; s < 32; ++s) {
      float4 c = cen4[t + (s << 8)];
      #pragma unroll
      for (int r = 0; r < 8; ++r) {
        u32 k = d2key(me[r], c);
        if (k <= Ur[r]) {
          u32 pos = atomicAdd(scnt, 1u);
          atomicAdd(&scnt_r[r], 1u);
          if (pos < 2048u)
            comp[pos] = ((u64)r << 45) | (((u64)k) << 13) | (u32)(t + (s << 8));
        }
      }
    }
    __syncthreads();
    const int cnt = (int)*scnt;

    if (cnt <= 2048) {
      u32 off[8];
      off[0] = 0;
      #pragma unroll
      for (int r = 1; r < 8; ++r) off[r] = off[r-1] + scnt_r[r-1];
      for (int i = t; i < cnt; i += 256) {
        u64 mev = comp[i];
        int rk = 0;
        int j2 = 0;
        for (; j2 + 2 <= cnt; j2 += 2) {
          ulonglong2 pr = *(const ulonglong2*)&comp[j2];
          rk += (pr.x < mev) ? 1 : 0;
          rk += (pr.y < mev) ? 1 : 0;
        }
        if (j2 < cnt) rk += (comp[j2] < mev) ? 1 : 0;
        int r = (int)(mev >> 45);
        int rank = rk - (int)off[r];
        if (rank < KNB) idxo[(row0 + r)*KNB + rank] = (int)(mev & 0x1FFFull);
      }
    } else {
      // overflow fallback (never taken statistically): exact per-row extract-min
      for (int r = 0; r < 8; ++r) {
        float4 mer = cen4[row0 + r];
        u32 taken = 0;
        for (int kk2 = 0; kk2 < KNB; ++kk2) {
          u64 lk = 0xFFFFFFFFFFFFFFFFull;
          for (int s = 0; s < 32; ++s) {
            if (taken & (1u << s)) continue;
            float4 c = cen4[t + (s << 8)];
            u64 kx = (((u64)d2key(mer, c)) << 13) | (u32)(t + (s << 8));
            lk = kx < lk ? kx : lk;
          }
          #pragma unroll
          for (int m = 1; m < 64; m <<= 1) {
            u64 o = shflx64(lk, m);
            lk = o < lk ? o : lk;
          }
          if (lane == 0) wred[w] = lk;
          __syncthreads();
          if (t == 0) {
            u64 w0 = wred[0] < wred[1] ? wred[0] : wred[1];
            u64 w1 = wred[2] < wred[3] ? wred[2] : wred[3];
            *winner = w0 < w1 ? w0 : w1;
            idxo[(row0 + r)*KNB + kk2] = (int)(*winner & 0x1FFFull);
          }
          __syncthreads();
          u64 jw = *winner & 0x1FFFull;
          if (((u32)jw & 255u) == (u32)t) taken |= 1u << ((u32)jw >> 8);
          __syncthreads();
        }
      }
    }
    return;
  }

  // ================= qkv path =================
  u16* sE = (u16*)pool;                 // 32*128 u16 (8 KiB), swizzled
  float* spart = (float*)(pool + 8192); // [4][32]
  const int l15 = lane & 15, l4 = lane >> 4;
  const int e0 = (blockIdx.x - E_N/8) * 32;
  const int colw = w * 32;

  // stage ef tile
  {
    const int srow = t >> 3, sb = t & 7;
    const float4* src = (const float4*)(ef + (size_t)(e0 + srow)*HID + sb*16);
    #pragma unroll
    for (int g = 0; g < 2; ++g) {
      float4 v0 = src[g*2], v1 = src[g*2+1];
      u16x8 vv;
      vv[0]=f2bf(v0.x); vv[1]=f2bf(v0.y); vv[2]=f2bf(v0.z); vv[3]=f2bf(v0.w);
      vv[4]=f2bf(v1.x); vv[5]=f2bf(v1.y); vv[6]=f2bf(v1.z); vv[7]=f2bf(v1.w);
      int widx = (srow*128 + sb*16 + g*8) ^ ((srow & 7) << 3);
      *(u16x8*)(&sE[widx]) = vv;
    }
  }
  __syncthreads();

  // preload all A fragments (2 row-tiles x 4 k-slices)
  bf16x8 afq[2][4];
  #pragma unroll
  for (int rt = 0; rt < 2; ++rt) {
    int row = rt*16 + l15;
    #pragma unroll
    for (int ks = 0; ks < 4; ++ks) {
      int aidx = (row*128 + ks*32 + l4*8) ^ ((row & 7) << 3);
      afq[rt][ks] = *(const bf16x8*)(&sE[aidx]);
    }
  }

  f32x4 a2[2][2];
  auto gemm_panel = [&](const u16* __restrict__ P) {
    #pragma unroll
    for (int rt = 0; rt < 2; ++rt)
      #pragma unroll
      for (int ct = 0; ct < 2; ++ct) a2[rt][ct] = (f32x4){0.f,0.f,0.f,0.f};
    #pragma unroll
    for (int ks = 0; ks < 4; ++ks) {
      bf16x8 bfr[2];
      #pragma unroll
      for (int ct = 0; ct < 2; ++ct)
        bfr[ct] = *(const bf16x8*)(&P[(colw + ct*16 + l15)*128 + ks*32 + l4*8]);
      #pragma unroll
      for (int rt = 0; rt < 2; ++rt)
        #pragma unroll
        for (int ct = 0; ct < 2; ++ct)
          a2[rt][ct] = __builtin_amdgcn_mfma_f32_16x16x32_bf16(afq[rt][ks], bfr[ct], a2[rt][ct], 0, 0, 0);
    }
  };

  // q
  gemm_panel(Wqt);
  #pragma unroll
  for (int rt = 0; rt < 2; ++rt)
    #pragma unroll
    for (int r = 0; r < 4; ++r) {
      size_t e = e0 + rt*16 + l4*4 + r;
      #pragma unroll
      for (int ct = 0; ct < 2; ++ct)
        qf[e*HID + colw + ct*16 + l15] = a2[rt][ct][r];
    }
  // k
  gemm_panel(Wkt);
  #pragma unroll
  for (int rt = 0; rt < 2; ++rt)
    #pragma unroll
    for (int r = 0; r < 4; ++r) {
      size_t e = e0 + rt*16 + l4*4 + r;
      #pragma unroll
      for (int ct = 0; ct < 2; ++ct)
        kjp[e*256 + 128 + colw + ct*16 + l15] = f2bf(a2[rt][ct][r]);
    }
  // v
  gemm_panel(Wvt);
  #pragma unroll
  for (int rt = 0; rt < 2; ++rt)
    #pragma unroll
    for (int r = 0; r < 4; ++r) {
      size_t e = e0 + rt*16 + l4*4 + r;
      #pragma unroll
      for (int ct = 0; ct < 2; ++ct)
        vfb[e*HID + colw + ct*16 + l15] = f2bf(a2[rt][ct][r]);
    }
  // qW1 = ef@(Wq@W1q) + b1
  gemm_panel(Wqct);
  {
    float b1r[2];
    #pragma unroll
    for (int ct = 0; ct < 2; ++ct) b1r[ct] = b1[colw + ct*16 + l15];
    #pragma unroll
    for (int rt = 0; rt < 2; ++rt)
      #pragma unroll
      for (int r = 0; r < 4; ++r) {
        size_t e = e0 + rt*16 + l4*4 + r;
        #pragma unroll
        for (int ct = 0; ct < 2; ++ct)
          qW1[e*HID + colw + ct*16 + l15] = a2[rt][ct][r] + b1r[ct];
      }
  }
  // kW1 = ef@(Wk@W1k)
  gemm_panel(Wkct);
  #pragma unroll
  for (int rt = 0; rt < 2; ++rt)
    #pragma unroll
    for (int r = 0; r < 4; ++r) {
      size_t e = e0 + rt*16 + l4*4 + r;
      #pragma unroll
      for (int ct = 0; ct < 2; ++ct)
        kjp[e*256 + colw + ct*16 + l15] = f2bf(a2[rt][ct][r]);
    }
  // gates: g1 = silu(ef@(Wv@Wg1) + bg1); gate = sigmoid(g1.Wg2 + bg2)
  gemm_panel(Wvgt);
  {
    float bgr[2], w3r[2];
    #pragma unroll
    for (int ct = 0; ct < 2; ++ct) {
      int col = colw + ct*16 + l15;
      bgr[ct] = bg1[col]; w3r[ct] = Wg2[col];
    }
    #pragma unroll
    for (int rt = 0; rt < 2; ++rt)
      #pragma unroll
      for (int r = 0; r < 4; ++r) {
        float part = 0.f;
        #pragma unroll
        for (int ct = 0; ct < 2; ++ct) {
          float x = a2[rt][ct][r] + bgr[ct];
          float g = x / (1.0f + __expf(-x));
          part = fmaf(g, w3r[ct], part);
        }
        part += __shfl_xor(part, 1, 64);
        part += __shfl_xor(part, 2, 64);
        part += __shfl_xor(part, 4, 64);
        part += __shfl_xor(part, 8, 64);
        if (l15 == 0) spart[w*32 + rt*16 + l4*4 + r] = part;
      }
  }
  __syncthreads();
  if (t < 32)
    gates[e0 + t] = 1.0f / (1.0f + __expf(-(spart[t] + spart[32+t] + spart[64+t] + spart[96+t] + bg2[0])));
}

// ---------------- kernel 5: mega (MLP + softmax + combine + Wo-MFMA + LayerNorm), 4 edges/block ----------------
__global__ __launch_bounds__(512) void k_mega(
    const int* __restrict__ idx,
    const float* __restrict__ qf,
    const float4* __restrict__ cen4,
    const float* __restrict__ qW1, const u16* __restrict__ kjp,
    const u16* __restrict__ vfb, const float* __restrict__ gates,
    const u16* __restrict__ Wt1r, const u16* __restrict__ Wt2,
    const u16* __restrict__ Wot,
    const float* __restrict__ W1,
    const float* __restrict__ b2, const float* __restrict__ W3,
    const float* __restrict__ b3,
    const float* __restrict__ centers, const float* __restrict__ widths,
    const float* __restrict__ ef, const float* __restrict__ ec,
    const float* __restrict__ bo,
    const float* __restrict__ gamma, const float* __restrict__ beta,
    float* __restrict__ outf, float* __restrict__ outc) {
  __shared__ u16 sH[128*128];     // 32 KiB: kW1[j] tile -> in-place h tile
  __shared__ u16 sA[128*64];      // 16 KiB: rbf tile; aliased after GEMM1 drain:
  float* spart = (float*)sA;            // [4][128] col-slab partial scores (f32 0..511)
  float* swk   = (float*)sA + 512;      // [4][32]  softmax weights        (512..639)
  float* sred  = (float*)sA + 640;      // [8][2]   LN partial sums        (640..655)
  float* sWo   = (float*)sA + 656;      // [4][128] Wo-MFMA output         (656..1167)
  u16*   sUB   = (u16*)((float*)sA + 1168); // [16][136] bf16 upd tile, +8 u16 row pad
  __shared__ float sQW[4][128];   // 2 KiB
  __shared__ float sDot[128];
  __shared__ float sDist[128];
  __shared__ int   sIdx[128];

  const int t  = threadIdx.x;
  const int w  = t >> 6, l = t & 63;
  const int l15 = l & 15, l4 = l >> 4;
  const int c4 = w & 3, rh = w >> 2;
  const int rowbase = blockIdx.x * 128;
  const int eBase = rowbase >> 5;           // four edges per block

  // ---- stage: kW1[j] tile (vectorized gather -> sH), dot, dist, rbf -> sA ----
  const int srow = t >> 2, sb = t & 3;      // 128 rows x 4 threads
  const int sp = rowbase + srow;
  const int se = sp >> 5;
  const int sj = idx[sp];
  {
    const u16x8* kw = (const u16x8*)(kjp + (size_t)sj*256 + sb*32);
    #pragma unroll
    for (int g = 0; g < 4; ++g) {
      int widx = (srow*128 + sb*32 + g*8) ^ ((srow & 7) << 3);
      *(u16x8*)(&sH[widx]) = kw[g];
    }
  }
  // q.k dot: q f32 x k bf16 (packed row), 4 lanes/row
  const u16x8* kb = (const u16x8*)(kjp + (size_t)sj*256 + 128 + sb*32);
  const float4* q4 = (const float4*)(qf + (size_t)se*HID) + sb*8;
  float dt = 0.f;
  #pragma unroll
  for (int i = 0; i < 4; ++i) {
    u16x8 kv8 = kb[i];
    float4 qa = q4[i*2], qb = q4[i*2+1];
    dt += bf2f(kv8[0])*qa.x + bf2f(kv8[1])*qa.y + bf2f(kv8[2])*qa.z + bf2f(kv8[3])*qa.w
        + bf2f(kv8[4])*qb.x + bf2f(kv8[5])*qb.y + bf2f(kv8[6])*qb.z + bf2f(kv8[7])*qb.w;
  }
  dt += __shfl_xor(dt, 1, 64);
  dt += __shfl_xor(dt, 2, 64);
  // geometry
  float4 ce = cen4[se], cj = cen4[sj];
  float ddx = ce.x - cj.x, ddy = ce.y - cj.y, ddz = ce.z - cj.z;
  const float sdist = sqrtf(ddx*ddx + ddy*ddy + ddz*ddz);
  const float sincut = (sdist <= CUTF) ? 1.0f : 0.0f;
  if (sb == 0) { sDot[srow] = dt; sDist[srow] = sdist; }
  {
    u16 tmp[16];
    #pragma unroll
    for (int i4 = 0; i4 < 4; ++i4) {
      float4 cc = *(const float4*)(centers + sb*16 + i4*4);
      float4 ww = *(const float4*)(widths  + sb*16 + i4*4);
      float c4v[4] = {cc.x,cc.y,cc.z,cc.w}, w4[4] = {ww.x,ww.y,ww.z,ww.w};
      #pragma unroll
      for (int jj = 0; jj < 4; ++jj) {
        float df = sdist - c4v[jj];
        tmp[i4*4+jj] = f2bf(__expf(-w4[jj]*df*df) * sincut);
      }
    }
    #pragma unroll
    for (int g = 0; g < 2; ++g) {
      u16x8 vv;
      #pragma unroll
      for (int jj = 0; jj < 8; ++jj) vv[jj] = tmp[g*8+jj];
      int widx = (srow*64 + sb*16 + g*8) ^ ((srow & 7) << 3);
      *(u16x8*)(&sA[widx]) = vv;
    }
  }
  sQW[t >> 7][t & 127] = qW1[(size_t)(eBase + (t >> 7))*HID + (t & 127)];
  if (t < 128) sIdx[t] = idx[rowbase + t];

  // ---- LAST loads of the phase: vfb prefetch for the combine tail ----
  u32 vp[16];
  {
    const int eh2 = t >> 7, colp = t & 127;
    const int ib = rowbase + eh2*32;
    #pragma unroll
    for (int kk = 0; kk < 16; ++kk) {
      int j0 = idx[ib + 2*kk], j1 = idx[ib + 2*kk + 1];
      u32 a = vfb[(size_t)j0*HID + colp];
      u32 b = vfb[(size_t)j1*HID + colp];
      vp[kk] = a | (b << 16);
    }
  }
  __syncthreads();

  f32x4 acc[4][2];
  #pragma unroll
  for (int rt = 0; rt < 4; ++rt)
    #pragma unroll
    for (int ct = 0; ct < 2; ++ct) acc[rt][ct] = (f32x4){0.f,0.f,0.f,0.f};

  // ---- GEMM1: rbf (K=64) ----
  #pragma unroll
  for (int ks = 0; ks < 2; ++ks) {
    bf16x8 af[4], bfr[2];
    #pragma unroll
    for (int rt = 0; rt < 4; ++rt) {
      int row = rh*64 + rt*16 + l15;
      int aidx = (row*64 + ks*32 + l4*8) ^ ((row & 7) << 3);
      af[rt] = *(const bf16x8*)(&sA[aidx]);
    }
    #pragma unroll
    for (int ct = 0; ct < 2; ++ct) {
      int col = c4*32 + ct*16 + l15;
      bfr[ct] = *(const bf16x8*)(&Wt1r[col*64 + ks*32 + l4*8]);
    }
    #pragma unroll
    for (int rt = 0; rt < 4; ++rt)
      #pragma unroll
      for (int ct = 0; ct < 2; ++ct)
        acc[rt][ct] = __builtin_amdgcn_mfma_f32_16x16x32_bf16(af[rt], bfr[ct], acc[rt][ct], 0, 0, 0);
  }

  // ---- epilogue 1: x = acc + qW1[e] + kW1[j](sH in-place) + dot*w320; silu -> sH ----
  {
    float w320[2];
    #pragma unroll
    for (int ct = 0; ct < 2; ++ct) {
      int col = c4*32 + ct*16 + l15;
      w320[ct] = W1[320*HID + col];
    }
    #pragma unroll
    for (int rt = 0; rt < 4; ++rt) {
      #pragma unroll
      for (int r = 0; r < 4; ++r) {
        int row = rh*64 + rt*16 + l4*4 + r;
        float dv = sDot[row];
        int eh = row >> 5;
        #pragma unroll
        for (int ct = 0; ct < 2; ++ct) {
          int col = c4*32 + ct*16 + l15;
          int hidx = (row*128 + col) ^ ((row & 7) << 3);
          float x = acc[rt][ct][r] + sQW[eh][col] + bf2f(sH[hidx]) + dv*w320[ct];
          float h = x / (1.0f + __expf(-x));
          sH[hidx] = f2bf(h);
        }
      }
    }
  }
  __syncthreads();            // all GEMM1 sA reads done; sA alias region now usable

  #pragma unroll
  for (int rt = 0; rt < 4; ++rt)
    #pragma unroll
    for (int ct = 0; ct < 2; ++ct) acc[rt][ct] = (f32x4){0.f,0.f,0.f,0.f};

  // ---- GEMM2: h @ W2 ----
  #pragma unroll
  for (int ks = 0; ks < 4; ++ks) {
    bf16x8 af[4], bfr[2];
    #pragma unroll
    for (int rt = 0; rt < 4; ++rt) {
      int row = rh*64 + rt*16 + l15;
      int aidx = (row*128 + ks*32 + l4*8) ^ ((row & 7) << 3);
      af[rt] = *(const bf16x8*)(&sH[aidx]);
    }
    #pragma unroll
    for (int ct = 0; ct < 2; ++ct) {
      int col = c4*32 + ct*16 + l15;
      bfr[ct] = *(const bf16x8*)(&Wt2[col*128 + ks*32 + l4*8]);
    }
    #pragma unroll
    for (int rt = 0; rt < 4; ++rt)
      #pragma unroll
      for (int ct = 0; ct < 2; ++ct)
        acc[rt][ct] = __builtin_amdgcn_mfma_f32_16x16x32_bf16(af[rt], bfr[ct], acc[rt][ct], 0, 0, 0);
  }

  // ---- epilogue 2: silu, dot W3, reduce over this wave's 32 cols -> spart ----
  {
    float b2r[2], w3r[2];
    #pragma unroll
    for (int ct = 0; ct < 2; ++ct) {
      int col = c4*32 + ct*16 + l15;
      b2r[ct] = b2[col]; w3r[ct] = W3[col];
    }
    #pragma unroll
    for (int rt = 0; rt < 4; ++rt) {
      #pragma unroll
      for (int r = 0; r < 4; ++r) {
        float part = 0.f;
        #pragma unroll
        for (int ct = 0; ct < 2; ++ct) {
          float x = acc[rt][ct][r] + b2r[ct];
          float h = x / (1.0f + __expf(-x));
          part = fmaf(h, w3r[ct], part);
        }
        part += __shfl_xor(part, 1, 64);
        part += __shfl_xor(part, 2, 64);
        part += __shfl_xor(part, 4, 64);
        part += __shfl_xor(part, 8, 64);
        if (l15 == 0) spart[c4*128 + rh*64 + rt*16 + l4*4 + r] = part;
      }
    }
  }
  __syncthreads();

  // ---- softmax + coord update: wave w (<4) -> edge w ----
  if (w < 4 && l < 32) {
    const int eh = w;
    const int row = eh*32 + l;
    float raw = spart[row] + spart[128 + row] + spart[256 + row] + spart[384 + row] + b3[0];
    float sc = (sDist[row] <= CUTF) ? raw : 0.0f;
    float m = sc;
    #pragma unroll
    for (int mm = 1; mm < 32; mm <<= 1) m = fmaxf(m, __shfl_xor(m, mm, 64));
    m = fmaxf(m, 0.0f);
    float ex = __expf(sc - m);
    float Z = ex;
    #pragma unroll
    for (int mm = 1; mm < 32; mm <<= 1) Z += __shfl_xor(Z, mm, 64);
    Z += 8160.0f * __expf(-m);               // (E-K) zero-score tail
    float wv = ex / Z;
    swk[eh*32 + l] = wv;
    int j = sIdx[row];
    float g = wv * gates[j];
    float4 cee = cen4[eBase + eh], cjj = cen4[j];
    float cx = g*(cee.x - cjj.x), cy = g*(cee.y - cjj.y), cz = g*(cee.z - cjj.z);
    #pragma unroll
    for (int mm = 1; mm < 32; mm <<= 1) {
      cx += __shfl_xor(cx, mm, 64);
      cy += __shfl_xor(cy, mm, 64);
      cz += __shfl_xor(cz, mm, 64);
    }
    if (l == 0) {
      int e = eBase + eh;
      outc[e*3+0] = ec[e*3+0] + cx;
      outc[e*3+1] = ec[e*3+1] + cy;
      outc[e*3+2] = ec[e*3+2] + cz;
    }
  }
  __syncthreads();

  // ---- weighted V (prefetched regs) + residual -> sUB (bf16 upd tile, padded rows) ----
  {
    const int eh = t >> 7, col = t & 127;
    float acc2 = 0.f;
    #pragma unroll
    for (int kk = 0; kk < 16; ++kk) {
      acc2 = fmaf(swk[eh*32 + 2*kk],     bf2f((u16)(vp[kk] & 0xffffu)), acc2);
      acc2 = fmaf(swk[eh*32 + 2*kk + 1], bf2f((u16)(vp[kk] >> 16)),     acc2);
    }
    sUB[eh*136 + col] = f2bf(ef[(size_t)(eBase + eh)*HID + col] + acc2);
  }
  __syncthreads();

  // ---- Wo projection via MFMA: D[edge][col] = upd(bf16) @ Wo ----
  {
    f32x4 aw = (f32x4){0.f,0.f,0.f,0.f};
    #pragma unroll
    for (int ks = 0; ks < 4; ++ks) {
      bf16x8 afu = *(const bf16x8*)(&sUB[l15*136 + ks*32 + l4*8]);
      bf16x8 bfo = *(const bf16x8*)(&Wot[(size_t)(w*16 + l15)*128 + ks*32 + l4*8]);
      aw = __builtin_amdgcn_mfma_f32_16x16x32_bf16(afu, bfo, aw, 0, 0, 0);
    }
    if (l4 == 0) {                 // rows 0-3 = edges
      #pragma unroll
      for (int r = 0; r < 4; ++r)
        sWo[r*128 + w*16 + l15] = aw[r];
    }
  }
  __syncthreads();

  // ---- residual + LayerNorm ----
  {
    const int eh = t >> 7, o = t & 127;
    const int e = eBase + eh;
    float x = ef[(size_t)e*HID + o] + sWo[eh*128 + o] + bo[o];
    float s1 = x, s2 = x*x;
    #pragma unroll
    for (int m = 1; m < 64; m <<= 1) {
      s1 += __shfl_xor(s1, m, 64);
      s2 += __shfl_xor(s2, m, 64);
    }
    if (l == 0) { sred[w*2+0] = s1; sred[w*2+1] = s2; }
    __syncthreads();
    float t1 = sred[(eh*2)*2+0] + sred[(eh*2+1)*2+0];
    float t2 = sred[(eh*2)*2+1] + sred[(eh*2+1)*2+1];
    float mu = t1 * (1.0f/128.0f);
    float var = t2 * (1.0f/128.0f) - mu*mu;
    float rs = rsqrtf(var + LNEPS);
    outf[(size_t)e*HID + o] = (x - mu)*rs*gamma[o] + beta[o];
  }
}

extern "C" void kernel_launch(void* const* d_in, const int* in_sizes, int n_in,
                              void* d_out, int out_size, void* d_ws, size_t ws_size,
                              hipStream_t stream) {
  const float* ef   = (const float*)d_in[0];
  const float* ec   = (const float*)d_in[1];
  const float* nc   = (const float*)d_in[2];
  const float* Wq   = (const float*)d_in[3];
  const float* Wk   = (const float*)d_in[4];
  const float* Wv   = (const float*)d_in[5];
  const float* W1   = (const float*)d_in[6];
  const float* b1   = (const float*)d_in[7];
  const float* W2   = (const float*)d_in[8];
  const float* b2   = (const float*)d_in[9];
  const float* W3   = (const float*)d_in[10];
  const float* b3   = (const float*)d_in[11];
  const float* Wg1  = (const float*)d_in[12];
  const float* bg1  = (const float*)d_in[13];
  const float* Wg2  = (const float*)d_in[14];
  const float* bg2  = (const float*)d_in[15];
  const float* Wo   = (const float*)d_in[16];
  const float* bo   = (const float*)d_in[17];
  const float* gamma= (const float*)d_in[18];
  const float* beta = (const float*)d_in[19];
  const float* centers = (const float*)d_in[20];
  const float* widths  = (const float*)d_in[21];
  const int*   eidx    = (const int*)d_in[22];

  float* outf = (float*)d_out;
  float* outc = outf + (size_t)E_N * HID;

  // workspace layout (16B-aligned chunks first)
  float4* cen4 = (float4*)d_ws;                        // 8192 * 16B
  u16*   kjp   = (u16*)(cen4 + E_N);                   // E * 256 bf16 (4 MB)
  u16*   vfb   = kjp + (size_t)E_N*256;                // E * 128 bf16 (2 MB)
  u16*   Wt1r  = vfb + (size_t)E_N*128;                // 128*64 bf16
  u16*   Wt2   = Wt1r + 128*64;                        // 128*128 bf16
  u16*   Wqt   = Wt2  + 128*128;
  u16*   Wkt   = Wqt  + 128*128;
  u16*   Wvt   = Wkt  + 128*128;
  u16*   Wqct  = Wvt  + 128*128;
  u16*   Wkct  = Wqct + 128*128;
  u16*   Wvgt  = Wkct + 128*128;
  u16*   Wot   = Wvgt + 128*128;
  int*   idx   = (int*)(Wot + 128*128);
  float* qf    = (float*)(idx + E_N*KNB);
  float* qW1   = qf + (size_t)E_N*HID;
  float* gates = qW1 + (size_t)E_N*HID;

  k_pre<<<672, 256, 0, stream>>>(W1, W2, Wq, Wk, Wv, Wg1, Wo, nc, eidx,
                                 Wt1r, Wt2, Wqt, Wkt, Wvt, Wqct, Wkct, Wvgt, Wot, cen4);
  k_tq<<<E_N/8 + E_N/32, 256, 0, stream>>>(cen4, idx, ef, Wqt, Wkt, Wvt, Wqct, Wkct, Wvgt,
                                           b1, bg1, Wg2, bg2, qf, qW1, kjp, vfb, gates);
  k_mega<<<E_N*KNB/128, 512, 0, stream>>>(idx, qf, cen4, qW1, kjp, vfb, gates, Wt1r, Wt2,
                                          Wot, W1, b2, W3, b3, centers, widths, ef, ec,
                                          bo, gamma, beta, outf, outc);
}

// Round 21
// 174.584 us; speedup vs baseline: 1.2035x; 1.0020x over previous
//
#include <hip/hip_runtime.h>
#include <math.h>

#define E_N   8192
#define HID   128
#define NRAD  64
#define KNB   32
#define CUTF  10.0f
#define LNEPS 1e-5f

typedef unsigned short u16;
typedef unsigned int   u32;
typedef unsigned long long u64;
typedef __bf16 bf16x8 __attribute__((ext_vector_type(8)));
typedef u16    u16x8  __attribute__((ext_vector_type(8)));
typedef float  f32x4  __attribute__((ext_vector_type(4)));

__device__ __forceinline__ u16 f2bf(float f) {          // native HW cvt (RNE)
  __bf16 h = (__bf16)f;
  return __builtin_bit_cast(u16, h);
}
__device__ __forceinline__ float bf2f(u16 v) {
  return __uint_as_float(((u32)v) << 16);
}

__device__ __forceinline__ u64 shflx64(u64 v, int m) {
  int lo = __shfl_xor((int)(v & 0xffffffffull), m, 64);
  int hi = __shfl_xor((int)(v >> 32), m, 64);
  return ((u64)(unsigned)hi << 32) | (unsigned)lo;
}

// monotone-u32 key of squared distance; fmaf-pinned so pass1/pass2 agree bitwise
__device__ __forceinline__ u32 d2key(const float4 me, const float4 c) {
  float dot = fmaf(me.x, c.x, fmaf(me.y, c.y, me.z * c.z));
  float d2  = fmaf(-2.0f, dot, me.w + c.w);     // gram trick, as in reference
  u32 u = __float_as_uint(d2);
  return u ^ (((u32)((int)u >> 31)) | 0x80000000u);
}

// ---------------- kernel 0: merged prep (bf16 panels / fused products / centers) ----------------
__global__ __launch_bounds__(256) void k_pre(
    const float* __restrict__ W1, const float* __restrict__ W2,
    const float* __restrict__ Wq, const float* __restrict__ Wk,
    const float* __restrict__ Wv, const float* __restrict__ Wg1,
    const float* __restrict__ Wo,
    const float* __restrict__ nc, const int* __restrict__ ei,
    u16* __restrict__ Wt1r, u16* __restrict__ Wt2,
    u16* __restrict__ Wqt, u16* __restrict__ Wkt, u16* __restrict__ Wvt,
    u16* __restrict__ Wqct, u16* __restrict__ Wkct, u16* __restrict__ Wvgt,
    u16* __restrict__ Wot,
    float4* __restrict__ cen4) {
  const int b = blockIdx.x, t = threadIdx.x;
  if (b < 128) {
    if (t < 64)       Wt1r[b*64 + t]      = f2bf(W1[(256+t)*HID + b]);   // rbf rows 256..319
    else if (t < 192) Wt2[b*HID + (t-64)] = f2bf(W2[(t-64)*HID + b]);
  } else if (b < 256) {
    const int r = b - 128, o = t & 127;
    float a = 0.f;
    if (t < 128) {
      #pragma unroll 8
      for (int m = 0; m < 128; ++m) a = fmaf(Wq[r*128+m], W1[m*128+o], a);
      Wqct[o*128 + r] = f2bf(a);
    } else {
      #pragma unroll 8
      for (int m = 0; m < 128; ++m) a = fmaf(Wk[r*128+m], W1[(128+m)*128+o], a);
      Wkct[o*128 + r] = f2bf(a);
    }
  } else if (b < 384) {
    const int r = b - 256;
    if (t < 128) {
      float a = 0.f;
      #pragma unroll 8
      for (int m = 0; m < 128; ++m) a = fmaf(Wv[r*128+m], Wg1[m*128+t], a);
      Wvgt[t*128 + r] = f2bf(a);
    }
  } else if (b < 512) {
    const int c = b - 384;
    if (t < 128) Wqt[c*128 + t]       = f2bf(Wq[t*128 + c]);
    else         Wkt[c*128 + (t-128)] = f2bf(Wk[(t-128)*128 + c]);
  } else if (b < 640) {
    const int c = b - 512;
    if (t < 128) Wvt[c*128 + t]       = f2bf(Wv[t*128 + c]);
    else         Wot[c*128 + (t-128)] = f2bf(Wo[(t-128)*128 + c]);
  } else {
    const int e = (b - 640)*256 + t;
    if (e < E_N) {
      int a = ei[e], bb = ei[E_N + e];
      float x = (nc[a*3+0] + nc[bb*3+0]) * 0.5f;
      float y = (nc[a*3+1] + nc[bb*3+1]) * 0.5f;
      float z = (nc[a*3+2] + nc[bb*3+2]) * 0.5f;
      cen4[e] = make_float4(x, y, z, x*x + y*y + z*z);
    }
  }
}

// ---------------- kernel 2+3 merged: top-K (blocks 0..1023) | qkv projections (1024..1279) ----------------
__global__ __launch_bounds__(256) void k_tq(
    const float4* __restrict__ cen4, int* __restrict__ idxo,
    const float* __restrict__ ef,
    const u16* __restrict__ Wqt, const u16* __restrict__ Wkt, const u16* __restrict__ Wvt,
    const u16* __restrict__ Wqct, const u16* __restrict__ Wkct, const u16* __restrict__ Wvgt,
    const float* __restrict__ b1, const float* __restrict__ bg1,
    const float* __restrict__ Wg2, const float* __restrict__ bg2,
    float* __restrict__ qf, float* __restrict__ qW1,
    u16* __restrict__ kjp, u16* __restrict__ vfb, float* __restrict__ gates) {
  __shared__ __align__(16) char pool[24704];
  const int t = threadIdx.x;
  const int lane = t & 63, w = t >> 6;

  if (blockIdx.x < E_N/8) {
    // ================= top-K path =================
    u64* comp   = (u64*)pool;                    // 2048 * 8
    u32* smin   = (u32*)(pool + 16384);          // 8*256 * 4
    u64* wred   = (u64*)(pool + 24576);          // 4 * 8
    u64* winner = (u64*)(pool + 24608);
    u32* sU     = (u32*)(pool + 24616);          // 8 * 4
    u32* scnt   = (u32*)(pool + 24648);
    u32* scnt_r = (u32*)(pool + 24652);          // 8 * 4

    const int row0 = blockIdx.x * 8;
    if (t == 0) *scnt = 0;
    if (t < 8) scnt_r[t] = 0;

    float4 me[8];
    #pragma unroll
    for (int r = 0; r < 8; ++r) me[r] = cen4[row0 + r];

    // pass 1: running mins for 8 rows
    u32 mn[8];
    #pragma unroll
    for (int r = 0; r < 8; ++r) mn[r] = 0xFFFFFFFFu;
    for (int s = 0; s < 32; ++s) {
      float4 c = cen4[t + (s << 8)];
      #pragma unroll
      for (int r = 0; r < 8; ++r) {
        u32 k = d2key(me[r], c);
        mn[r] = k < mn[r] ? k : mn[r];
      }
    }
    #pragma unroll
    for (int r = 0; r < 8; ++r) smin[r*256 + t] = mn[r];
    __syncthreads();

    // per-row bound: wave w handles rows 2w, 2w+1; in-wave radix bisect
    #pragma unroll
    for (int rr = 0; rr < 2; ++rr) {
      const int r = w*2 + rr;
      uint4 vv = *(const uint4*)&smin[r*256 + lane*4];
      u32 P = 0;
      u32 rem = 31;
      #pragma unroll 1
      for (int b = 31; b >= 12; --b) {
        u32 bit = 1u << b;
        bool pm0 = ((u64)(vv.x ^ P) >> (b+1)) == 0ull;
        bool pm1 = ((u64)(vv.y ^ P) >> (b+1)) == 0ull;
        bool pm2 = ((u64)(vv.z ^ P) >> (b+1)) == 0ull;
        bool pm3 = ((u64)(vv.w ^ P) >> (b+1)) == 0ull;
        u32 c0 = (u32)__popcll(__ballot(pm0 && !(vv.x & bit)))
               + (u32)__popcll(__ballot(pm1 && !(vv.y & bit)))
               + (u32)__popcll(__ballot(pm2 && !(vv.z & bit)))
               + (u32)__popcll(__ballot(pm3 && !(vv.w & bit)));
        if (rem >= c0) { P |= bit; rem -= c0; }
      }
      if (lane == 0) sU[r] = P | 0xFFFu;
    }
    __syncthreads();

    // pass 2: recompute keys, compact survivors
    u32 Ur[8];
    #pragma unroll
    for (int r = 0; r < 8; ++r) Ur[r] = sU[r];
    for (int s = 0; s < 32; ++s) {
      float4 c = cen4[t + (s << 8)];
      #pragma unroll
      for (int r = 0; r < 8; ++r) {
        u32 k = d2key(me[r], c);
        if (k <= Ur[r]) {
          u32 pos = atomicAdd(scnt, 1u);
          atomicAdd(&scnt_r[r], 1u);
          if (pos < 2048u)
            comp[pos] = ((u64)r << 45) | (((u64)k) << 13) | (u32)(t + (s << 8));
        }
      }
    }
    __syncthreads();
    const int cnt = (int)*scnt;

    if (cnt <= 2048) {
      u32 off[8];
      off[0] = 0;
      #pragma unroll
      for (int r = 1; r < 8; ++r) off[r] = off[r-1] + scnt_r[r-1];
      for (int i = t; i < cnt; i += 256) {
        u64 mev = comp[i];
        int rk = 0;
        int j2 = 0;
        for (; j2 + 2 <= cnt; j2 += 2) {
          ulonglong2 pr = *(const ulonglong2*)&comp[j2];
          rk += (pr.x < mev) ? 1 : 0;
          rk += (pr.y < mev) ? 1 : 0;
        }
        if (j2 < cnt) rk += (comp[j2] < mev) ? 1 : 0;
        int r = (int)(mev >> 45);
        int rank = rk - (int)off[r];
        if (rank < KNB) idxo[(row0 + r)*KNB + rank] = (int)(mev & 0x1FFFull);
      }
    } else {
      // overflow fallback (never taken statistically): exact per-row extract-min
      for (int r = 0; r < 8; ++r) {
        float4 mer = cen4[row0 + r];
        u32 taken = 0;
        for (int kk2 = 0; kk2 < KNB; ++kk2) {
          u64 lk = 0xFFFFFFFFFFFFFFFFull;
          for (int s = 0; s < 32; ++s) {
            if (taken & (1u << s)) continue;
            float4 c = cen4[t + (s << 8)];
            u64 kx = (((u64)d2key(mer, c)) << 13) | (u32)(t + (s << 8));
            lk = kx < lk ? kx : lk;
          }
          #pragma unroll
          for (int m = 1; m < 64; m <<= 1) {
            u64 o = shflx64(lk, m);
            lk = o < lk ? o : lk;
          }
          if (lane == 0) wred[w] = lk;
          __syncthreads();
          if (t == 0) {
            u64 w0 = wred[0] < wred[1] ? wred[0] : wred[1];
            u64 w1 = wred[2] < wred[3] ? wred[2] : wred[3];
            *winner = w0 < w1 ? w0 : w1;
            idxo[(row0 + r)*KNB + kk2] = (int)(*winner & 0x1FFFull);
          }
          __syncthreads();
          u64 jw = *winner & 0x1FFFull;
          if (((u32)jw & 255u) == (u32)t) taken |= 1u << ((u32)jw >> 8);
          __syncthreads();
        }
      }
    }
    return;
  }

  // ================= qkv path =================
  u16* sE = (u16*)pool;                 // 32*128 u16 (8 KiB), swizzled
  float* spart = (float*)(pool + 8192); // [4][32]
  const int l15 = lane & 15, l4 = lane >> 4;
  const int e0 = (blockIdx.x - E_N/8) * 32;
  const int colw = w * 32;

  // stage ef tile
  {
    const int srow = t >> 3, sb = t & 7;
    const float4* src = (const float4*)(ef + (size_t)(e0 + srow)*HID + sb*16);
    #pragma unroll
    for (int g = 0; g < 2; ++g) {
      float4 v0 = src[g*2], v1 = src[g*2+1];
      u16x8 vv;
      vv[0]=f2bf(v0.x); vv[1]=f2bf(v0.y); vv[2]=f2bf(v0.z); vv[3]=f2bf(v0.w);
      vv[4]=f2bf(v1.x); vv[5]=f2bf(v1.y); vv[6]=f2bf(v1.z); vv[7]=f2bf(v1.w);
      int widx = (srow*128 + sb*16 + g*8) ^ ((srow & 7) << 3);
      *(u16x8*)(&sE[widx]) = vv;
    }
  }
  __syncthreads();

  // preload all A fragments (2 row-tiles x 4 k-slices)
  bf16x8 afq[2][4];
  #pragma unroll
  for (int rt = 0; rt < 2; ++rt) {
    int row = rt*16 + l15;
    #pragma unroll
    for (int ks = 0; ks < 4; ++ks) {
      int aidx = (row*128 + ks*32 + l4*8) ^ ((row & 7) << 3);
      afq[rt][ks] = *(const bf16x8*)(&sE[aidx]);
    }
  }

  f32x4 a2[2][2];
  auto gemm_panel = [&](const u16* __restrict__ P) {
    #pragma unroll
    for (int rt = 0; rt < 2; ++rt)
      #pragma unroll
      for (int ct = 0; ct < 2; ++ct) a2[rt][ct] = (f32x4){0.f,0.f,0.f,0.f};
    #pragma unroll
    for (int ks = 0; ks < 4; ++ks) {
      bf16x8 bfr[2];
      #pragma unroll
      for (int ct = 0; ct < 2; ++ct)
        bfr[ct] = *(const bf16x8*)(&P[(colw + ct*16 + l15)*128 + ks*32 + l4*8]);
      #pragma unroll
      for (int rt = 0; rt < 2; ++rt)
        #pragma unroll
        for (int ct = 0; ct < 2; ++ct)
          a2[rt][ct] = __builtin_amdgcn_mfma_f32_16x16x32_bf16(afq[rt][ks], bfr[ct], a2[rt][ct], 0, 0, 0);
    }
  };

  // q
  gemm_panel(Wqt);
  #pragma unroll
  for (int rt = 0; rt < 2; ++rt)
    #pragma unroll
    for (int r = 0; r < 4; ++r) {
      size_t e = e0 + rt*16 + l4*4 + r;
      #pragma unroll
      for (int ct = 0; ct < 2; ++ct)
        qf[e*HID + colw + ct*16 + l15] = a2[rt][ct][r];
    }
  // k
  gemm_panel(Wkt);
  #pragma unroll
  for (int rt = 0; rt < 2; ++rt)
    #pragma unroll
    for (int r = 0; r < 4; ++r) {
      size_t e = e0 + rt*16 + l4*4 + r;
      #pragma unroll
      for (int ct = 0; ct < 2; ++ct)
        kjp[e*256 + 128 + colw + ct*16 + l15] = f2bf(a2[rt][ct][r]);
    }
  // v
  gemm_panel(Wvt);
  #pragma unroll
  for (int rt = 0; rt < 2; ++rt)
    #pragma unroll
    for (int r = 0; r < 4; ++r) {
      size_t e = e0 + rt*16 + l4*4 + r;
      #pragma unroll
      for (int ct = 0; ct < 2; ++ct)
        vfb[e*HID + colw + ct*16 + l15] = f2bf(a2[rt][ct][r]);
    }
  // qW1 = ef@(Wq@W1q) + b1
  gemm_panel(Wqct);
  {
    float b1r[2];
    #pragma unroll
    for (int ct = 0; ct < 2; ++ct) b1r[ct] = b1[colw + ct*16 + l15];
    #pragma unroll
    for (int rt = 0; rt < 2; ++rt)
      #pragma unroll
      for (int r = 0; r < 4; ++r) {
        size_t e = e0 + rt*16 + l4*4 + r;
        #pragma unroll
        for (int ct = 0; ct < 2; ++ct)
          qW1[e*HID + colw + ct*16 + l15] = a2[rt][ct][r] + b1r[ct];
      }
  }
  // kW1 = ef@(Wk@W1k)
  gemm_panel(Wkct);
  #pragma unroll
  for (int rt = 0; rt < 2; ++rt)
    #pragma unroll
    for (int r = 0; r < 4; ++r) {
      size_t e = e0 + rt*16 + l4*4 + r;
      #pragma unroll
      for (int ct = 0; ct < 2; ++ct)
        kjp[e*256 + colw + ct*16 + l15] = f2bf(a2[rt][ct][r]);
    }
  // gates: g1 = silu(ef@(Wv@Wg1) + bg1); gate = sigmoid(g1.Wg2 + bg2)
  gemm_panel(Wvgt);
  {
    float bgr[2], w3r[2];
    #pragma unroll
    for (int ct = 0; ct < 2; ++ct) {
      int col = colw + ct*16 + l15;
      bgr[ct] = bg1[col]; w3r[ct] = Wg2[col];
    }
    #pragma unroll
    for (int rt = 0; rt < 2; ++rt)
      #pragma unroll
      for (int r = 0; r < 4; ++r) {
        float part = 0.f;
        #pragma unroll
        for (int ct = 0; ct < 2; ++ct) {
          float x = a2[rt][ct][r] + bgr[ct];
          float g = x / (1.0f + __expf(-x));
          part = fmaf(g, w3r[ct], part);
        }
        part += __shfl_xor(part, 1, 64);
        part += __shfl_xor(part, 2, 64);
        part += __shfl_xor(part, 4, 64);
        part += __shfl_xor(part, 8, 64);
        if (l15 == 0) spart[w*32 + rt*16 + l4*4 + r] = part;
      }
  }
  __syncthreads();
  if (t < 32)
    gates[e0 + t] = 1.0f / (1.0f + __expf(-(spart[t] + spart[32+t] + spart[64+t] + spart[96+t] + bg2[0])));
}

// ---------------- kernel 5: mega (MLP + softmax + combine + Wo-MFMA + LayerNorm), 4 edges/block ----------------
// Softmax/coord phase is zero-global-load: gates[j], cdiff, and the in-cut
// mask are persisted at stage time (gather latency hides under the GEMMs).
__global__ __launch_bounds__(512) void k_mega(
    const int* __restrict__ idx,
    const float* __restrict__ qf,
    const float4* __restrict__ cen4,
    const float* __restrict__ qW1, const u16* __restrict__ kjp,
    const u16* __restrict__ vfb, const float* __restrict__ gates,
    const u16* __restrict__ Wt1r, const u16* __restrict__ Wt2,
    const u16* __restrict__ Wot,
    const float* __restrict__ W1,
    const float* __restrict__ b2, const float* __restrict__ W3,
    const float* __restrict__ b3,
    const float* __restrict__ centers, const float* __restrict__ widths,
    const float* __restrict__ ef, const float* __restrict__ ec,
    const float* __restrict__ bo,
    const float* __restrict__ gamma, const float* __restrict__ beta,
    float* __restrict__ outf, float* __restrict__ outc) {
  __shared__ u16 sH[128*128];     // 32 KiB: kW1[j] tile -> in-place h tile
  __shared__ u16 sA[128*64];      // 16 KiB: rbf tile; aliased after GEMM1 drain:
  float* spart = (float*)sA;            // [4][128] col-slab partial scores (f32 0..511)
  float* swk   = (float*)sA + 512;      // [4][32]  softmax weights        (512..639)
  float* sred  = (float*)sA + 640;      // [8][2]   LN partial sums        (640..655)
  float* sWo   = (float*)sA + 656;      // [4][128] Wo-MFMA output         (656..1167)
  u16*   sUB   = (u16*)((float*)sA + 1168); // [16][136] bf16 upd tile, +8 u16 row pad
  __shared__ float sQW[4][128];   // 2 KiB
  __shared__ float sDot[128];
  __shared__ float sGt[128];      // gates[j] per row (staged)
  __shared__ float sCd0[128], sCd1[128], sCd2[128];   // cdiff per row (staged)
  __shared__ int   sIdxM[128];    // j | (out-of-cut << 30)

  const int t  = threadIdx.x;
  const int w  = t >> 6, l = t & 63;
  const int l15 = l & 15, l4 = l >> 4;
  const int c4 = w & 3, rh = w >> 2;
  const int rowbase = blockIdx.x * 128;
  const int eBase = rowbase >> 5;           // four edges per block

  // ---- stage: kW1[j] tile (vectorized gather -> sH), dot, dist, rbf -> sA ----
  const int srow = t >> 2, sb = t & 3;      // 128 rows x 4 threads
  const int sp = rowbase + srow;
  const int se = sp >> 5;
  const int sj = idx[sp];
  {
    const u16x8* kw = (const u16x8*)(kjp + (size_t)sj*256 + sb*32);
    #pragma unroll
    for (int g = 0; g < 4; ++g) {
      int widx = (srow*128 + sb*32 + g*8) ^ ((srow & 7) << 3);
      *(u16x8*)(&sH[widx]) = kw[g];
    }
  }
  // q.k dot: q f32 x k bf16 (packed row), 4 lanes/row
  const u16x8* kb = (const u16x8*)(kjp + (size_t)sj*256 + 128 + sb*32);
  const float4* q4 = (const float4*)(qf + (size_t)se*HID) + sb*8;
  float dt = 0.f;
  #pragma unroll
  for (int i = 0; i < 4; ++i) {
    u16x8 kv8 = kb[i];
    float4 qa = q4[i*2], qb = q4[i*2+1];
    dt += bf2f(kv8[0])*qa.x + bf2f(kv8[1])*qa.y + bf2f(kv8[2])*qa.z + bf2f(kv8[3])*qa.w
        + bf2f(kv8[4])*qb.x + bf2f(kv8[5])*qb.y + bf2f(kv8[6])*qb.z + bf2f(kv8[7])*qb.w;
  }
  dt += __shfl_xor(dt, 1, 64);
  dt += __shfl_xor(dt, 2, 64);
  // geometry
  float4 ce = cen4[se], cj = cen4[sj];
  float ddx = ce.x - cj.x, ddy = ce.y - cj.y, ddz = ce.z - cj.z;
  const float sdist = sqrtf(ddx*ddx + ddy*ddy + ddz*ddz);
  const float sincut = (sdist <= CUTF) ? 1.0f : 0.0f;
  if (sb == 0)      { sDot[srow] = dt; sIdxM[srow] = sj | ((sdist <= CUTF) ? 0 : (1 << 30)); }
  else if (sb == 1) { sGt[srow] = gates[sj]; }
  else if (sb == 2) { sCd0[srow] = ddx; sCd1[srow] = ddy; }
  else              { sCd2[srow] = ddz; }
  {
    u16 tmp[16];
    #pragma unroll
    for (int i4 = 0; i4 < 4; ++i4) {
      float4 cc = *(const float4*)(centers + sb*16 + i4*4);
      float4 ww = *(const float4*)(widths  + sb*16 + i4*4);
      float c4v[4] = {cc.x,cc.y,cc.z,cc.w}, w4[4] = {ww.x,ww.y,ww.z,ww.w};
      #pragma unroll
      for (int jj = 0; jj < 4; ++jj) {
        float df = sdist - c4v[jj];
        tmp[i4*4+jj] = f2bf(__expf(-w4[jj]*df*df) * sincut);
      }
    }
    #pragma unroll
    for (int g = 0; g < 2; ++g) {
      u16x8 vv;
      #pragma unroll
      for (int jj = 0; jj < 8; ++jj) vv[jj] = tmp[g*8+jj];
      int widx = (srow*64 + sb*16 + g*8) ^ ((srow & 7) << 3);
      *(u16x8*)(&sA[widx]) = vv;
    }
  }
  sQW[t >> 7][t & 127] = qW1[(size_t)(eBase + (t >> 7))*HID + (t & 127)];

  // ---- LAST loads of the phase: vfb prefetch for the combine tail ----
  u32 vp[16];
  {
    const int eh2 = t >> 7, colp = t & 127;
    const int ib = rowbase + eh2*32;
    #pragma unroll
    for (int kk = 0; kk < 16; ++kk) {
      int j0 = idx[ib + 2*kk], j1 = idx[ib + 2*kk + 1];
      u32 a = vfb[(size_t)j0*HID + colp];
      u32 b = vfb[(size_t)j1*HID + colp];
      vp[kk] = a | (b << 16);
    }
  }
  __syncthreads();

  f32x4 acc[4][2];
  #pragma unroll
  for (int rt = 0; rt < 4; ++rt)
    #pragma unroll
    for (int ct = 0; ct < 2; ++ct) acc[rt][ct] = (f32x4){0.f,0.f,0.f,0.f};

  // ---- GEMM1: rbf (K=64) ----
  #pragma unroll
  for (int ks = 0; ks < 2; ++ks) {
    bf16x8 af[4], bfr[2];
    #pragma unroll
    for (int rt = 0; rt < 4; ++rt) {
      int row = rh*64 + rt*16 + l15;
      int aidx = (row*64 + ks*32 + l4*8) ^ ((row & 7) << 3);
      af[rt] = *(const bf16x8*)(&sA[aidx]);
    }
    #pragma unroll
    for (int ct = 0; ct < 2; ++ct) {
      int col = c4*32 + ct*16 + l15;
      bfr[ct] = *(const bf16x8*)(&Wt1r[col*64 + ks*32 + l4*8]);
    }
    #pragma unroll
    for (int rt = 0; rt < 4; ++rt)
      #pragma unroll
      for (int ct = 0; ct < 2; ++ct)
        acc[rt][ct] = __builtin_amdgcn_mfma_f32_16x16x32_bf16(af[rt], bfr[ct], acc[rt][ct], 0, 0, 0);
  }

  // ---- epilogue 1: x = acc + qW1[e] + kW1[j](sH in-place) + dot*w320; silu -> sH ----
  {
    float w320[2];
    #pragma unroll
    for (int ct = 0; ct < 2; ++ct) {
      int col = c4*32 + ct*16 + l15;
      w320[ct] = W1[320*HID + col];
    }
    #pragma unroll
    for (int rt = 0; rt < 4; ++rt) {
      #pragma unroll
      for (int r = 0; r < 4; ++r) {
        int row = rh*64 + rt*16 + l4*4 + r;
        float dv = sDot[row];
        int eh = row >> 5;
        #pragma unroll
        for (int ct = 0; ct < 2; ++ct) {
          int col = c4*32 + ct*16 + l15;
          int hidx = (row*128 + col) ^ ((row & 7) << 3);
          float x = acc[rt][ct][r] + sQW[eh][col] + bf2f(sH[hidx]) + dv*w320[ct];
          float h = x / (1.0f + __expf(-x));
          sH[hidx] = f2bf(h);
        }
      }
    }
  }
  __syncthreads();            // all GEMM1 sA reads done; sA alias region now usable

  #pragma unroll
  for (int rt = 0; rt < 4; ++rt)
    #pragma unroll
    for (int ct = 0; ct < 2; ++ct) acc[rt][ct] = (f32x4){0.f,0.f,0.f,0.f};

  // ---- GEMM2: h @ W2 ----
  #pragma unroll
  for (int ks = 0; ks < 4; ++ks) {
    bf16x8 af[4], bfr[2];
    #pragma unroll
    for (int rt = 0; rt < 4; ++rt) {
      int row = rh*64 + rt*16 + l15;
      int aidx = (row*128 + ks*32 + l4*8) ^ ((row & 7) << 3);
      af[rt] = *(const bf16x8*)(&sH[aidx]);
    }
    #pragma unroll
    for (int ct = 0; ct < 2; ++ct) {
      int col = c4*32 + ct*16 + l15;
      bfr[ct] = *(const bf16x8*)(&Wt2[col*128 + ks*32 + l4*8]);
    }
    #pragma unroll
    for (int rt = 0; rt < 4; ++rt)
      #pragma unroll
      for (int ct = 0; ct < 2; ++ct)
        acc[rt][ct] = __builtin_amdgcn_mfma_f32_16x16x32_bf16(af[rt], bfr[ct], acc[rt][ct], 0, 0, 0);
  }

  // ---- epilogue 2: silu, dot W3, reduce over this wave's 32 cols -> spart ----
  {
    float b2r[2], w3r[2];
    #pragma unroll
    for (int ct = 0; ct < 2; ++ct) {
      int col = c4*32 + ct*16 + l15;
      b2r[ct] = b2[col]; w3r[ct] = W3[col];
    }
    #pragma unroll
    for (int rt = 0; rt < 4; ++rt) {
      #pragma unroll
      for (int r = 0; r < 4; ++r) {
        float part = 0.f;
        #pragma unroll
        for (int ct = 0; ct < 2; ++ct) {
          float x = acc[rt][ct][r] + b2r[ct];
          float h = x / (1.0f + __expf(-x));
          part = fmaf(h, w3r[ct], part);
        }
        part += __shfl_xor(part, 1, 64);
        part += __shfl_xor(part, 2, 64);
        part += __shfl_xor(part, 4, 64);
        part += __shfl_xor(part, 8, 64);
        if (l15 == 0) spart[c4*128 + rh*64 + rt*16 + l4*4 + r] = part;
      }
    }
  }
  __syncthreads();

  // ---- softmax + coord update (zero global loads): wave w (<4) -> edge w ----
  if (w < 4 && l < 32) {
    const int eh = w;
    const int row = eh*32 + l;
    float raw = spart[row] + spart[128 + row] + spart[256 + row] + spart[384 + row] + b3[0];
    int im = sIdxM[row];
    float sc = (im & (1 << 30)) ? 0.0f : raw;
    float m = sc;
    #pragma unroll
    for (int mm = 1; mm < 32; mm <<= 1) m = fmaxf(m, __shfl_xor(m, mm, 64));
    m = fmaxf(m, 0.0f);
    float ex = __expf(sc - m);
    float Z = ex;
    #pragma unroll
    for (int mm = 1; mm < 32; mm <<= 1) Z += __shfl_xor(Z, mm, 64);
    Z += 8160.0f * __expf(-m);               // (E-K) zero-score tail
    float wv = ex / Z;
    swk[eh*32 + l] = wv;
    float g = wv * sGt[row];
    float cx = g*sCd0[row], cy = g*sCd1[row], cz = g*sCd2[row];
    #pragma unroll
    for (int mm = 1; mm < 32; mm <<= 1) {
      cx += __shfl_xor(cx, mm, 64);
      cy += __shfl_xor(cy, mm, 64);
      cz += __shfl_xor(cz, mm, 64);
    }
    if (l == 0) {
      int e = eBase + eh;
      outc[e*3+0] = ec[e*3+0] + cx;
      outc[e*3+1] = ec[e*3+1] + cy;
      outc[e*3+2] = ec[e*3+2] + cz;
    }
  }
  __syncthreads();

  // ---- weighted V (prefetched regs) + residual -> sUB (bf16 upd tile, padded rows) ----
  {
    const int eh = t >> 7, col = t & 127;
    float acc2 = 0.f;
    #pragma unroll
    for (int kk = 0; kk < 16; ++kk) {
      acc2 = fmaf(swk[eh*32 + 2*kk],     bf2f((u16)(vp[kk] & 0xffffu)), acc2);
      acc2 = fmaf(swk[eh*32 + 2*kk + 1], bf2f((u16)(vp[kk] >> 16)),     acc2);
    }
    sUB[eh*136 + col] = f2bf(ef[(size_t)(eBase + eh)*HID + col] + acc2);
  }
  __syncthreads();

  // ---- Wo projection via MFMA: D[edge][col] = upd(bf16) @ Wo ----
  {
    f32x4 aw = (f32x4){0.f,0.f,0.f,0.f};
    #pragma unroll
    for (int ks = 0; ks < 4; ++ks) {
      bf16x8 afu = *(const bf16x8*)(&sUB[l15*136 + ks*32 + l4*8]);
      bf16x8 bfo = *(const bf16x8*)(&Wot[(size_t)(w*16 + l15)*128 + ks*32 + l4*8]);
      aw = __builtin_amdgcn_mfma_f32_16x16x32_bf16(afu, bfo, aw, 0, 0, 0);
    }
    if (l4 == 0) {                 // rows 0-3 = edges
      #pragma unroll
      for (int r = 0; r < 4; ++r)
        sWo[r*128 + w*16 + l15] = aw[r];
    }
  }
  __syncthreads();

  // ---- residual + LayerNorm ----
  {
    const int eh = t >> 7, o = t & 127;
    const int e = eBase + eh;
    float x = ef[(size_t)e*HID + o] + sWo[eh*128 + o] + bo[o];
    float s1 = x, s2 = x*x;
    #pragma unroll
    for (int m = 1; m < 64; m <<= 1) {
      s1 += __shfl_xor(s1, m, 64);
      s2 += __shfl_xor(s2, m, 64);
    }
    if (l == 0) { sred[w*2+0] = s1; sred[w*2+1] = s2; }
    __syncthreads();
    float t1 = sred[(eh*2)*2+0] + sred[(eh*2+1)*2+0];
    float t2 = sred[(eh*2)*2+1] + sred[(eh*2+1)*2+1];
    float mu = t1 * (1.0f/128.0f);
    float var = t2 * (1.0f/128.0f) - mu*mu;
    float rs = rsqrtf(var + LNEPS);
    outf[(size_t)e*HID + o] = (x - mu)*rs*gamma[o] + beta[o];
  }
}

extern "C" void kernel_launch(void* const* d_in, const int* in_sizes, int n_in,
                              void* d_out, int out_size, void* d_ws, size_t ws_size,
                              hipStream_t stream) {
  const float* ef   = (const float*)d_in[0];
  const float* ec   = (const float*)d_in[1];
  const float* nc   = (const float*)d_in[2];
  const float* Wq   = (const float*)d_in[3];
  const float* Wk   = (const float*)d_in[4];
  const float* Wv   = (const float*)d_in[5];
  const float* W1   = (const float*)d_in[6];
  const float* b1   = (const float*)d_in[7];
  const float* W2   = (const float*)d_in[8];
  const float* b2   = (const float*)d_in[9];
  const float* W3   = (const float*)d_in[10];
  const float* b3   = (const float*)d_in[11];
  const float* Wg1  = (const float*)d_in[12];
  const float* bg1  = (const float*)d_in[13];
  const float* Wg2  = (const float*)d_in[14];
  const float* bg2  = (const float*)d_in[15];
  const float* Wo   = (const float*)d_in[16];
  const float* bo   = (const float*)d_in[17];
  const float* gamma= (const float*)d_in[18];
  const float* beta = (const float*)d_in[19];
  const float* centers = (const float*)d_in[20];
  const float* widths  = (const float*)d_in[21];
  const int*   eidx    = (const int*)d_in[22];

  float* outf = (float*)d_out;
  float* outc = outf + (size_t)E_N * HID;

  // workspace layout (16B-aligned chunks first)
  float4* cen4 = (float4*)d_ws;                        // 8192 * 16B
  u16*   kjp   = (u16*)(cen4 + E_N);                   // E * 256 bf16 (4 MB)
  u16*   vfb   = kjp + (size_t)E_N*256;                // E * 128 bf16 (2 MB)
  u16*   Wt1r  = vfb + (size_t)E_N*128;                // 128*64 bf16
  u16*   Wt2   = Wt1r + 128*64;                        // 128*128 bf16
  u16*   Wqt   = Wt2  + 128*128;
  u16*   Wkt   = Wqt  + 128*128;
  u16*   Wvt   = Wkt  + 128*128;
  u16*   Wqct  = Wvt  + 128*128;
  u16*   Wkct  = Wqct + 128*128;
  u16*   Wvgt  = Wkct + 128*128;
  u16*   Wot   = Wvgt + 128*128;
  int*   idx   = (int*)(Wot + 128*128);
  float* qf    = (float*)(idx + E_N*KNB);
  float* qW1   = qf + (size_t)E_N*HID;
  float* gates = qW1 + (size_t)E_N*HID;

  k_pre<<<672, 256, 0, stream>>>(W1, W2, Wq, Wk, Wv, Wg1, Wo, nc, eidx,
                                 Wt1r, Wt2, Wqt, Wkt, Wvt, Wqct, Wkct, Wvgt, Wot, cen4);
  k_tq<<<E_N/8 + E_N/32, 256, 0, stream>>>(cen4, idx, ef, Wqt, Wkt, Wvt, Wqct, Wkct, Wvgt,
                                           b1, bg1, Wg2, bg2, qf, qW1, kjp, vfb, gates);
  k_mega<<<E_N*KNB/128, 512, 0, stream>>>(idx, qf, cen4, qW1, kjp, vfb, gates, Wt1r, Wt2,
                                          Wot, W1, b2, W3, b3, centers, widths, ef, ec,
                                          bo, gamma, beta, outf, outc);
}